// Round 6
// baseline (529.732 us; speedup 1.0000x reference)
//
#include <hip/hip_runtime.h>
#include <math.h>

#define N_CELLS 100000
#define N_EDGES 1600000
#define FDIM 32
#define NEG_SLOPE 0.2f
#define NSEG (2 * N_CELLS)          // counts/offsets for both branches concatenated
#define SCAN_BLOCK 2048             // elements per scan block (256 thr x 8)
#define NSCAN_BLOCKS ((NSEG + SCAN_BLOCK - 1) / SCAN_BLOCK)   // 98
#define EDGE_BLOCKS ((2 * N_EDGES) / 256)                     // 12500 (exact)
#define NBIN 16
#define SEG_PER_BIN (NSEG / NBIN)   // 12500
#define P2_BLKS 800                 // pass-2 blocks per bin (stride loop covers any size)

__device__ __forceinline__ float leaky(float v) {
    return v > 0.f ? v : NEG_SLOPE * v;
}

// Kernel 1 (fused): h = x@W (both branches), per-node attention scores,
// AND src histogram. Grid: 12500 x 256 exactly covers 100000 rows (8/block)
// and 3.2M edge slots.
__global__ void k_fused(const float* __restrict__ x,
                        const float* __restrict__ Wirr, const float* __restrict__ Wsol,
                        const float* __restrict__ att_irr, const float* __restrict__ att_sol,
                        const int* __restrict__ do_idx, const int* __restrict__ up_idx,
                        float* __restrict__ h_irr, float* __restrict__ h_sol,
                        float* __restrict__ s_src_irr, float* __restrict__ s_tgt_irr,
                        float* __restrict__ s_src_sol, float* __restrict__ s_tgt_sol,
                        int* __restrict__ counts) {
    __shared__ float sWirr[FDIM * FDIM], sWsol[FDIM * FDIM];
    __shared__ float sAi[2 * FDIM], sAs[2 * FDIM];
    int t = threadIdx.x;
    for (int i = t; i < FDIM * FDIM; i += 256) { sWirr[i] = Wirr[i]; sWsol[i] = Wsol[i]; }
    if (t < 2 * FDIM) { sAi[t] = att_irr[t]; sAs[t] = att_sol[t]; }
    __syncthreads();

    // --- histogram of src for both branches ---
    int tid = blockIdx.x * 256 + t;
    if (tid < N_EDGES) atomicAdd(&counts[do_idx[tid]], 1);
    else atomicAdd(&counts[N_CELLS + up_idx[tid - N_EDGES]], 1);

    // --- h + scores: one wave handles 2 rows (32 lanes per row) ---
    int wave = t >> 6, lane = t & 63, halfsel = lane >> 5, f = lane & 31;
    int row = blockIdx.x * 8 + wave * 2 + halfsel;
    const float* xr = x + (size_t)row * FDIM;
    float hi = 0.f, hs = 0.f;
#pragma unroll
    for (int k = 0; k < FDIM; ++k) {
        float xv = xr[k];
        hi += xv * sWirr[k * FDIM + f];
        hs += xv * sWsol[k * FDIM + f];
    }
    h_irr[(size_t)row * FDIM + f] = hi;
    h_sol[(size_t)row * FDIM + f] = hs;

    float pi0 = hi * sAi[f], pi1 = hi * sAi[FDIM + f];
    float ps0 = hs * sAs[f], ps1 = hs * sAs[FDIM + f];
#pragma unroll
    for (int m = 16; m >= 1; m >>= 1) {
        pi0 += __shfl_xor(pi0, m);
        pi1 += __shfl_xor(pi1, m);
        ps0 += __shfl_xor(ps0, m);
        ps1 += __shfl_xor(ps1, m);
    }
    if (f == 0) {
        s_src_irr[row] = pi0;
        s_tgt_irr[row] = pi1;
        s_src_sol[row] = ps0;
        s_tgt_sol[row] = ps1;
    }
}

// Scan a: per-block exclusive scan of counts (2048 elems/block) + block sums.
__global__ void k_scan_a(const int* __restrict__ counts, int* __restrict__ offsets,
                         int* __restrict__ blksums) {
    __shared__ int sdata[256];
    int t = threadIdx.x;
    int base = blockIdx.x * SCAN_BLOCK + t * 8;
    int v[8];
    int sum = 0;
#pragma unroll
    for (int j = 0; j < 8; ++j) {
        v[j] = (base + j < NSEG) ? counts[base + j] : 0;
        sum += v[j];
    }
    sdata[t] = sum;
    __syncthreads();
    for (int off = 1; off < 256; off <<= 1) {
        int xv = (t >= off) ? sdata[t - off] : 0;
        __syncthreads();
        sdata[t] += xv;
        __syncthreads();
    }
    int excl = (t == 0) ? 0 : sdata[t - 1];
    if (t == 255) blksums[blockIdx.x] = sdata[255];
    int run = excl;
#pragma unroll
    for (int j = 0; j < 8; ++j) {
        if (base + j < NSEG) offsets[base + j] = run;
        run += v[j];
    }
}

// Scan b: exclusive scan of the block sums (single block).
__global__ void k_scan_b(int* __restrict__ blksums) {
    __shared__ int s[128];
    int t = threadIdx.x;
    s[t] = (t < NSCAN_BLOCKS) ? blksums[t] : 0;
    __syncthreads();
    for (int off = 1; off < 128; off <<= 1) {
        int xv = (t >= off) ? s[t - off] : 0;
        __syncthreads();
        s[t] += xv;
        __syncthreads();
    }
    if (t < NSCAN_BLOCKS) blksums[t] = (t == 0) ? 0 : s[t - 1];
}

// Scan c: add block offsets; copy into cursor; init per-bin append cursors.
__global__ void k_scan_c(int* __restrict__ offsets, int* __restrict__ cursor,
                         const int* __restrict__ blksums, int* __restrict__ bin_cursor) {
    int i = blockIdx.x * 256 + threadIdx.x;
    if (i < NSEG) {
        int vv = offsets[i] + blksums[i >> 11];
        offsets[i] = vv;
        cursor[i] = vv;
        if (i % SEG_PER_BIN == 0) bin_cursor[i / SEG_PER_BIN] = vv;
    }
}

// Pass 1 of the cache-aware counting sort: append packed (local_seg,tgt)
// records to 16 range-bins. Block-aggregated appends (LDS slot assignment +
// one global atomic per block per bin) make the writes an append-only log —
// lines fill densely in time, so they write back once regardless of the
// random segment order. Bin regions are exactly sized (cursor init = range
// start offset), so no overflow is possible.
__global__ void k_bin(const int* __restrict__ do_idx, const int* __restrict__ up_idx,
                      int* __restrict__ bin_cursor, unsigned int* __restrict__ bin_buf) {
    __shared__ unsigned int lcount[NBIN];
    __shared__ unsigned int lbase[NBIN];
    int t = threadIdx.x;
    if (t < NBIN) lcount[t] = 0u;
    __syncthreads();
    int tid = blockIdx.x * 256 + t;    // exact grid: 2*N_EDGES
    int seg, tg;
    if (tid < N_EDGES) {
        seg = do_idx[tid];
        tg = do_idx[N_EDGES + tid];
    } else {
        int e = tid - N_EDGES;
        seg = N_CELLS + up_idx[e];
        tg = up_idx[N_EDGES + e];
    }
    int bin = seg / SEG_PER_BIN;
    int local = seg - bin * SEG_PER_BIN;           // < 12500 -> 14 bits
    unsigned int rec = ((unsigned int)local << 17) | (unsigned int)tg;  // tgt < 2^17
    unsigned int slot = atomicAdd(&lcount[bin], 1u);
    __syncthreads();
    if (t < NBIN) lbase[t] = (unsigned int)atomicAdd(&bin_cursor[t], (int)lcount[t]);
    __syncthreads();
    bin_buf[lbase[bin] + slot] = rec;
}

// Pass 2: per-bin scatter into final CSR slots. bin = blockIdx&15 keeps each
// bin's blocks on one XCD (round-robin dispatch), and the per-bin working set
// (1.6MB bin stream + 800KB CSR slice + 50KB cursors) fits that XCD's 4MB L2,
// so dirty CSR lines survive until fully written.
__global__ void k_scatter2(const unsigned int* __restrict__ bin_buf,
                           const int* __restrict__ offsets,
                           int* __restrict__ cursor, int* __restrict__ csr_tgt) {
    int bin = blockIdx.x & (NBIN - 1);
    int blk = blockIdx.x >> 4;                     // 0..P2_BLKS-1
    int start = offsets[bin * SEG_PER_BIN];
    int end = (bin == NBIN - 1) ? 2 * N_EDGES : offsets[(bin + 1) * SEG_PER_BIN];
    for (int idx = start + blk * 256 + threadIdx.x; idx < end; idx += P2_BLKS * 256) {
        unsigned int rec = bin_buf[idx];
        int seg = bin * SEG_PER_BIN + (int)(rec >> 17);
        int tg = (int)(rec & 0x1FFFFu);
        int pos = atomicAdd(&cursor[seg], 1);
        csr_tgt[pos] = tg;
    }
}

// Per-branch accumulation with WAVE-UNIFORM control flow.
// Phase A: lane i holds edge i's (target, score); exact online max per chunk.
// Phase B: uniform loops; half-selection via shuffle SOURCE index (i+2j+half),
// so every __shfl executes with all 64 lanes active. Tail pairs clamp the
// source lane and zero the weight (predication, never divergent shuffles).
__device__ __forceinline__ float branch_acc(int seg, int n, int lane, int f, int half,
                                            const int* __restrict__ csr_tgt,
                                            const int* __restrict__ offsets,
                                            const int* __restrict__ counts,
                                            const float* __restrict__ s_src,
                                            const float* __restrict__ s_tgt,
                                            const float* __restrict__ h) {
    int beg = offsets[seg];
    int deg = counts[seg];
    float ssrc = s_src[n];
    float num = 0.f, den = 0.f, Mrun = -INFINITY;
    for (int base = 0; base < deg; base += 64) {
        int m = deg - base;
        if (m > 64) m = 64;
        int te = 0;
        float ev = -INFINITY;
        if (lane < m) {
            te = csr_tgt[beg + base + lane];
            ev = leaky(ssrc + s_tgt[te]);
        }
        // exact chunk max (allreduce over the wave)
        float cm = ev;
#pragma unroll
        for (int d = 32; d >= 1; d >>= 1) cm = fmaxf(cm, __shfl_xor(cm, d));
        float newM = fmaxf(Mrun, cm);
        float scale = __expf(Mrun - newM);   // 0 on first chunk (num=den=0)
        num *= scale;
        den *= scale;
        Mrun = newM;
        float we = __expf(ev - newM);        // 0 for lanes >= m (ev = -inf)

        int i = 0;
        for (; i + 15 < m; i += 16) {        // 8 independent gathers per lane
            int  t0 = __shfl(te, i +  0 + half), t1 = __shfl(te, i +  2 + half);
            int  t2 = __shfl(te, i +  4 + half), t3 = __shfl(te, i +  6 + half);
            int  t4 = __shfl(te, i +  8 + half), t5 = __shfl(te, i + 10 + half);
            int  t6 = __shfl(te, i + 12 + half), t7 = __shfl(te, i + 14 + half);
            float w0 = __shfl(we, i +  0 + half), w1 = __shfl(we, i +  2 + half);
            float w2 = __shfl(we, i +  4 + half), w3 = __shfl(we, i +  6 + half);
            float w4 = __shfl(we, i +  8 + half), w5 = __shfl(we, i + 10 + half);
            float w6 = __shfl(we, i + 12 + half), w7 = __shfl(we, i + 14 + half);
            float v0 = h[(size_t)t0 * FDIM + f], v1 = h[(size_t)t1 * FDIM + f];
            float v2 = h[(size_t)t2 * FDIM + f], v3 = h[(size_t)t3 * FDIM + f];
            float v4 = h[(size_t)t4 * FDIM + f], v5 = h[(size_t)t5 * FDIM + f];
            float v6 = h[(size_t)t6 * FDIM + f], v7 = h[(size_t)t7 * FDIM + f];
            num += w0 * v0 + w1 * v1 + w2 * v2 + w3 * v3;
            num += w4 * v4 + w5 * v5 + w6 * v6 + w7 * v7;
            den += w0 + w1 + w2 + w3 + w4 + w5 + w6 + w7;
        }
        for (; i + 7 < m; i += 8) {          // 4 independent gathers per lane
            int  t0 = __shfl(te, i + 0 + half), t1 = __shfl(te, i + 2 + half);
            int  t2 = __shfl(te, i + 4 + half), t3 = __shfl(te, i + 6 + half);
            float w0 = __shfl(we, i + 0 + half), w1 = __shfl(we, i + 2 + half);
            float w2 = __shfl(we, i + 4 + half), w3 = __shfl(we, i + 6 + half);
            float v0 = h[(size_t)t0 * FDIM + f], v1 = h[(size_t)t1 * FDIM + f];
            float v2 = h[(size_t)t2 * FDIM + f], v3 = h[(size_t)t3 * FDIM + f];
            num += w0 * v0 + w1 * v1 + w2 * v2 + w3 * v3;
            den += w0 + w1 + w2 + w3;
        }
        for (; i < m; i += 2) {              // uniform pair tail, clamped source
            int idx = i + half;
            int safe = (idx < m) ? idx : i;
            int tt = __shfl(te, safe);
            float ww = __shfl(we, safe);
            ww = (idx < m) ? ww : 0.f;
            num += ww * h[(size_t)tt * FDIM + f];
            den += ww;
        }
    }
    num += __shfl_xor(num, 32);
    den += __shfl_xor(den, 32);
    return num / (den + 1e-10f);
}

// Final aggregate: one 64-lane wave per node; ELU fused; single out write.
__global__ void k_node_aggregate(const int* __restrict__ csr_tgt,
                                 const int* __restrict__ offsets, const int* __restrict__ counts,
                                 const float* __restrict__ s_src_irr, const float* __restrict__ s_tgt_irr,
                                 const float* __restrict__ s_src_sol, const float* __restrict__ s_tgt_sol,
                                 const float* __restrict__ h_irr, const float* __restrict__ h_sol,
                                 float* __restrict__ out) {
    int wave = threadIdx.x >> 6;
    int lane = threadIdx.x & 63;
    int n = blockIdx.x * 4 + wave;     // grid 25000 exact
    int f = lane & 31;
    int half = lane >> 5;

    float res = branch_acc(n, n, lane, f, half, csr_tgt, offsets, counts,
                           s_src_irr, s_tgt_irr, h_irr);
    res += branch_acc(N_CELLS + n, n, lane, f, half, csr_tgt, offsets, counts,
                      s_src_sol, s_tgt_sol, h_sol);
    res = res > 0.f ? res : __expf(res) - 1.f;   // ELU
    if (half == 0) out[(size_t)n * FDIM + f] = res;
}

extern "C" void kernel_launch(void* const* d_in, const int* in_sizes, int n_in,
                              void* d_out, int out_size, void* d_ws, size_t ws_size,
                              hipStream_t stream) {
    const float* x = (const float*)d_in[0];
    const int* do_index = (const int*)d_in[1];
    const int* up_index = (const int*)d_in[2];
    const float* Wirr = (const float*)d_in[3];
    const float* Wsol = (const float*)d_in[4];
    const float* att_irr = (const float*)d_in[5];
    const float* att_sol = (const float*)d_in[6];
    float* out = (float*)d_out;

    // Workspace partition
    float* ws = (float*)d_ws;
    float* h_irr = ws;                                   // N*F
    float* h_sol = h_irr + (size_t)N_CELLS * FDIM;       // N*F
    float* s_src_irr = h_sol + (size_t)N_CELLS * FDIM;   // N
    float* s_tgt_irr = s_src_irr + N_CELLS;              // N
    float* s_src_sol = s_tgt_irr + N_CELLS;              // N
    float* s_tgt_sol = s_src_sol + N_CELLS;              // N
    int* counts = (int*)(s_tgt_sol + N_CELLS);           // NSEG
    int* offsets = counts + NSEG;                        // NSEG
    int* cursor = offsets + NSEG;                        // NSEG
    int* blksums = cursor + NSEG;                        // 128
    int* bin_cursor = blksums + 128;                     // NBIN
    int* csr_tgt = bin_cursor + NBIN;                    // 2*N_EDGES
    unsigned int* bin_buf = (unsigned int*)(csr_tgt + 2 * N_EDGES);  // 2*N_EDGES

    hipMemsetAsync(counts, 0, NSEG * sizeof(int), stream);

    // K1: fused h + scores + histogram
    hipLaunchKernelGGL(k_fused, dim3(EDGE_BLOCKS), dim3(256), 0, stream,
                       x, Wirr, Wsol, att_irr, att_sol, do_index, up_index,
                       h_irr, h_sol, s_src_irr, s_tgt_irr, s_src_sol, s_tgt_sol,
                       counts);

    // K2: exclusive scan of counts -> offsets (+cursor copy, +bin cursor init)
    hipLaunchKernelGGL(k_scan_a, dim3(NSCAN_BLOCKS), dim3(256), 0, stream,
                       counts, offsets, blksums);
    hipLaunchKernelGGL(k_scan_b, dim3(1), dim3(128), 0, stream, blksums);
    hipLaunchKernelGGL(k_scan_c, dim3((NSEG + 255) / 256), dim3(256), 0, stream,
                       offsets, cursor, blksums, bin_cursor);

    // K3a: bin edges by segment range (append-only coalesced writes)
    hipLaunchKernelGGL(k_bin, dim3(EDGE_BLOCKS), dim3(256), 0, stream,
                       do_index, up_index, bin_cursor, bin_buf);

    // K3b: per-bin scatter into CSR (L2-resident per-XCD working set)
    hipLaunchKernelGGL(k_scatter2, dim3(NBIN * P2_BLKS), dim3(256), 0, stream,
                       bin_buf, offsets, cursor, csr_tgt);

    // K4: per-node aggregate + ELU (1 wave/node, 4 waves/block -> exact grid)
    hipLaunchKernelGGL(k_node_aggregate, dim3(N_CELLS / 4), dim3(256), 0, stream,
                       csr_tgt, offsets, counts,
                       s_src_irr, s_tgt_irr, s_src_sol, s_tgt_sol,
                       h_irr, h_sol, out);
}

// Round 7
// 455.984 us; speedup vs baseline: 1.1617x; 1.1617x over previous
//
#include <hip/hip_runtime.h>
#include <math.h>

#define N_CELLS 100000
#define N_EDGES 1600000
#define FDIM 32
#define NEG_SLOPE 0.2f
#define NSEG (2 * N_CELLS)          // counts/offsets for both branches concatenated
#define SCAN_BLOCK 2048             // elements per scan block (256 thr x 8)
#define NSCAN_BLOCKS ((NSEG + SCAN_BLOCK - 1) / SCAN_BLOCK)   // 98
#define EDGE_BLOCKS ((2 * N_EDGES) / 256)                     // 12500 (exact)
#define NBIN 8
#define SEG_PER_BIN (NSEG / NBIN)   // 25000 (< 2^15, tgt < 2^17 -> 32-bit record)
#define EPT 4                       // edges per thread in k_bin
#define BIN_BLOCKS ((2 * N_EDGES) / (256 * EPT))              // 3125 (exact)
#define P2_BLKS 800                 // pass-2 blocks per bin (stride loop covers any size)

__device__ __forceinline__ float leaky(float v) {
    return v > 0.f ? v : NEG_SLOPE * v;
}

// Kernel 1 (fused): h = x@W (both branches), per-node attention scores,
// AND src histogram. Grid: 12500 x 256 exactly covers 100000 rows (8/block)
// and 3.2M edge slots.
__global__ void k_fused(const float* __restrict__ x,
                        const float* __restrict__ Wirr, const float* __restrict__ Wsol,
                        const float* __restrict__ att_irr, const float* __restrict__ att_sol,
                        const int* __restrict__ do_idx, const int* __restrict__ up_idx,
                        float* __restrict__ h_irr, float* __restrict__ h_sol,
                        float* __restrict__ s_src_irr, float* __restrict__ s_tgt_irr,
                        float* __restrict__ s_src_sol, float* __restrict__ s_tgt_sol,
                        int* __restrict__ counts) {
    __shared__ float sWirr[FDIM * FDIM], sWsol[FDIM * FDIM];
    __shared__ float sAi[2 * FDIM], sAs[2 * FDIM];
    int t = threadIdx.x;
    for (int i = t; i < FDIM * FDIM; i += 256) { sWirr[i] = Wirr[i]; sWsol[i] = Wsol[i]; }
    if (t < 2 * FDIM) { sAi[t] = att_irr[t]; sAs[t] = att_sol[t]; }
    __syncthreads();

    // --- histogram of src for both branches ---
    int tid = blockIdx.x * 256 + t;
    if (tid < N_EDGES) atomicAdd(&counts[do_idx[tid]], 1);
    else atomicAdd(&counts[N_CELLS + up_idx[tid - N_EDGES]], 1);

    // --- h + scores: one wave handles 2 rows (32 lanes per row) ---
    int wave = t >> 6, lane = t & 63, halfsel = lane >> 5, f = lane & 31;
    int row = blockIdx.x * 8 + wave * 2 + halfsel;
    const float* xr = x + (size_t)row * FDIM;
    float hi = 0.f, hs = 0.f;
#pragma unroll
    for (int k = 0; k < FDIM; ++k) {
        float xv = xr[k];
        hi += xv * sWirr[k * FDIM + f];
        hs += xv * sWsol[k * FDIM + f];
    }
    h_irr[(size_t)row * FDIM + f] = hi;
    h_sol[(size_t)row * FDIM + f] = hs;

    float pi0 = hi * sAi[f], pi1 = hi * sAi[FDIM + f];
    float ps0 = hs * sAs[f], ps1 = hs * sAs[FDIM + f];
#pragma unroll
    for (int m = 16; m >= 1; m >>= 1) {
        pi0 += __shfl_xor(pi0, m);
        pi1 += __shfl_xor(pi1, m);
        ps0 += __shfl_xor(ps0, m);
        ps1 += __shfl_xor(ps1, m);
    }
    if (f == 0) {
        s_src_irr[row] = pi0;
        s_tgt_irr[row] = pi1;
        s_src_sol[row] = ps0;
        s_tgt_sol[row] = ps1;
    }
}

// Scan a: per-block exclusive scan of counts (2048 elems/block) + block sums.
__global__ void k_scan_a(const int* __restrict__ counts, int* __restrict__ offsets,
                         int* __restrict__ blksums) {
    __shared__ int sdata[256];
    int t = threadIdx.x;
    int base = blockIdx.x * SCAN_BLOCK + t * 8;
    int v[8];
    int sum = 0;
#pragma unroll
    for (int j = 0; j < 8; ++j) {
        v[j] = (base + j < NSEG) ? counts[base + j] : 0;
        sum += v[j];
    }
    sdata[t] = sum;
    __syncthreads();
    for (int off = 1; off < 256; off <<= 1) {
        int xv = (t >= off) ? sdata[t - off] : 0;
        __syncthreads();
        sdata[t] += xv;
        __syncthreads();
    }
    int excl = (t == 0) ? 0 : sdata[t - 1];
    if (t == 255) blksums[blockIdx.x] = sdata[255];
    int run = excl;
#pragma unroll
    for (int j = 0; j < 8; ++j) {
        if (base + j < NSEG) offsets[base + j] = run;
        run += v[j];
    }
}

// Scan b: exclusive scan of the block sums (single block).
__global__ void k_scan_b(int* __restrict__ blksums) {
    __shared__ int s[128];
    int t = threadIdx.x;
    s[t] = (t < NSCAN_BLOCKS) ? blksums[t] : 0;
    __syncthreads();
    for (int off = 1; off < 128; off <<= 1) {
        int xv = (t >= off) ? s[t - off] : 0;
        __syncthreads();
        s[t] += xv;
        __syncthreads();
    }
    if (t < NSCAN_BLOCKS) blksums[t] = (t == 0) ? 0 : s[t - 1];
}

// Scan c: add block offsets; copy into cursor; init per-bin append cursors
// (padded: one counter per 64B line to avoid same-line atomic serialization).
__global__ void k_scan_c(int* __restrict__ offsets, int* __restrict__ cursor,
                         const int* __restrict__ blksums, int* __restrict__ bin_cursor) {
    int i = blockIdx.x * 256 + threadIdx.x;
    if (i < NSEG) {
        int vv = offsets[i] + blksums[i >> 11];
        offsets[i] = vv;
        cursor[i] = vv;
        if (i % SEG_PER_BIN == 0) bin_cursor[(i / SEG_PER_BIN) * 16] = vv;
    }
}

// Pass 1 of the cache-aware counting sort: append packed (local_seg,tgt)
// records to 8 range-bins. Block-aggregated appends (LDS slot assignment +
// one global atomic per block per bin, cursors padded to separate cache
// lines) make the writes an append-only log: lines fill densely in time and
// write back once. 4 edges/thread -> only ~25K global atomics total.
__global__ void k_bin(const int* __restrict__ do_idx, const int* __restrict__ up_idx,
                      int* __restrict__ bin_cursor, unsigned int* __restrict__ bin_buf) {
    __shared__ unsigned int lcount[NBIN];
    __shared__ unsigned int lbase[NBIN];
    int t = threadIdx.x;
    if (t < NBIN) lcount[t] = 0u;
    __syncthreads();

    unsigned int recs[EPT];
    int bins[EPT];
    unsigned int slots[EPT];
    int base = blockIdx.x * (256 * EPT);
#pragma unroll
    for (int j = 0; j < EPT; ++j) {
        int tid = base + j * 256 + t;     // coalesced per j; grid covers 2*N_EDGES exactly
        int seg, tg;
        if (tid < N_EDGES) {
            seg = do_idx[tid];
            tg = do_idx[N_EDGES + tid];
        } else {
            int e = tid - N_EDGES;
            seg = N_CELLS + up_idx[e];
            tg = up_idx[N_EDGES + e];
        }
        int bin = seg / SEG_PER_BIN;
        int local = seg - bin * SEG_PER_BIN;          // < 25000 -> 15 bits
        recs[j] = ((unsigned int)local << 17) | (unsigned int)tg;  // tgt < 2^17
        bins[j] = bin;
        slots[j] = atomicAdd(&lcount[bin], 1u);
    }
    __syncthreads();
    if (t < NBIN) lbase[t] = (unsigned int)atomicAdd(&bin_cursor[t * 16], (int)lcount[t]);
    __syncthreads();
#pragma unroll
    for (int j = 0; j < EPT; ++j)
        bin_buf[lbase[bins[j]] + slots[j]] = recs[j];
}

// Pass 2: per-bin scatter into final CSR slots. bin = blockIdx&7 puts each
// bin on exactly one XCD (round-robin dispatch); per-XCD working set =
// 1.6MB bin stream + 1.6MB CSR slice + 100KB cursors ~ 3.3MB < 4MB L2,
// so dirty CSR lines survive until fully written.
__global__ void k_scatter2(const unsigned int* __restrict__ bin_buf,
                           const int* __restrict__ offsets,
                           int* __restrict__ cursor, int* __restrict__ csr_tgt) {
    int bin = blockIdx.x & (NBIN - 1);
    int blk = blockIdx.x >> 3;                     // 0..P2_BLKS-1
    int start = offsets[bin * SEG_PER_BIN];
    int end = (bin == NBIN - 1) ? 2 * N_EDGES : offsets[(bin + 1) * SEG_PER_BIN];
    for (int idx = start + blk * 256 + threadIdx.x; idx < end; idx += P2_BLKS * 256) {
        unsigned int rec = bin_buf[idx];
        int seg = bin * SEG_PER_BIN + (int)(rec >> 17);
        int tg = (int)(rec & 0x1FFFFu);
        int pos = atomicAdd(&cursor[seg], 1);
        csr_tgt[pos] = tg;
    }
}

// Per-branch accumulation with WAVE-UNIFORM control flow.
// Phase A: lane i holds edge i's (target, score); exact online max per chunk.
// Phase B: uniform loops; half-selection via shuffle SOURCE index (i+2j+half),
// so every __shfl executes with all 64 lanes active. Tail pairs clamp the
// source lane and zero the weight (predication, never divergent shuffles).
__device__ __forceinline__ float branch_acc(int seg, int n, int lane, int f, int half,
                                            const int* __restrict__ csr_tgt,
                                            const int* __restrict__ offsets,
                                            const int* __restrict__ counts,
                                            const float* __restrict__ s_src,
                                            const float* __restrict__ s_tgt,
                                            const float* __restrict__ h) {
    int beg = offsets[seg];
    int deg = counts[seg];
    float ssrc = s_src[n];
    float num = 0.f, den = 0.f, Mrun = -INFINITY;
    for (int base = 0; base < deg; base += 64) {
        int m = deg - base;
        if (m > 64) m = 64;
        int te = 0;
        float ev = -INFINITY;
        if (lane < m) {
            te = csr_tgt[beg + base + lane];
            ev = leaky(ssrc + s_tgt[te]);
        }
        // exact chunk max (allreduce over the wave)
        float cm = ev;
#pragma unroll
        for (int d = 32; d >= 1; d >>= 1) cm = fmaxf(cm, __shfl_xor(cm, d));
        float newM = fmaxf(Mrun, cm);
        float scale = __expf(Mrun - newM);   // 0 on first chunk (num=den=0)
        num *= scale;
        den *= scale;
        Mrun = newM;
        float we = __expf(ev - newM);        // 0 for lanes >= m (ev = -inf)

        int i = 0;
        for (; i + 15 < m; i += 16) {        // 8 independent gathers per lane
            int  t0 = __shfl(te, i +  0 + half), t1 = __shfl(te, i +  2 + half);
            int  t2 = __shfl(te, i +  4 + half), t3 = __shfl(te, i +  6 + half);
            int  t4 = __shfl(te, i +  8 + half), t5 = __shfl(te, i + 10 + half);
            int  t6 = __shfl(te, i + 12 + half), t7 = __shfl(te, i + 14 + half);
            float w0 = __shfl(we, i +  0 + half), w1 = __shfl(we, i +  2 + half);
            float w2 = __shfl(we, i +  4 + half), w3 = __shfl(we, i +  6 + half);
            float w4 = __shfl(we, i +  8 + half), w5 = __shfl(we, i + 10 + half);
            float w6 = __shfl(we, i + 12 + half), w7 = __shfl(we, i + 14 + half);
            float v0 = h[(size_t)t0 * FDIM + f], v1 = h[(size_t)t1 * FDIM + f];
            float v2 = h[(size_t)t2 * FDIM + f], v3 = h[(size_t)t3 * FDIM + f];
            float v4 = h[(size_t)t4 * FDIM + f], v5 = h[(size_t)t5 * FDIM + f];
            float v6 = h[(size_t)t6 * FDIM + f], v7 = h[(size_t)t7 * FDIM + f];
            num += w0 * v0 + w1 * v1 + w2 * v2 + w3 * v3;
            num += w4 * v4 + w5 * v5 + w6 * v6 + w7 * v7;
            den += w0 + w1 + w2 + w3 + w4 + w5 + w6 + w7;
        }
        for (; i + 7 < m; i += 8) {          // 4 independent gathers per lane
            int  t0 = __shfl(te, i + 0 + half), t1 = __shfl(te, i + 2 + half);
            int  t2 = __shfl(te, i + 4 + half), t3 = __shfl(te, i + 6 + half);
            float w0 = __shfl(we, i + 0 + half), w1 = __shfl(we, i + 2 + half);
            float w2 = __shfl(we, i + 4 + half), w3 = __shfl(we, i + 6 + half);
            float v0 = h[(size_t)t0 * FDIM + f], v1 = h[(size_t)t1 * FDIM + f];
            float v2 = h[(size_t)t2 * FDIM + f], v3 = h[(size_t)t3 * FDIM + f];
            num += w0 * v0 + w1 * v1 + w2 * v2 + w3 * v3;
            den += w0 + w1 + w2 + w3;
        }
        for (; i < m; i += 2) {              // uniform pair tail, clamped source
            int idx = i + half;
            int safe = (idx < m) ? idx : i;
            int tt = __shfl(te, safe);
            float ww = __shfl(we, safe);
            ww = (idx < m) ? ww : 0.f;
            num += ww * h[(size_t)tt * FDIM + f];
            den += ww;
        }
    }
    num += __shfl_xor(num, 32);
    den += __shfl_xor(den, 32);
    return num / (den + 1e-10f);
}

// Final aggregate: one 64-lane wave per node; ELU fused; single out write.
__global__ void k_node_aggregate(const int* __restrict__ csr_tgt,
                                 const int* __restrict__ offsets, const int* __restrict__ counts,
                                 const float* __restrict__ s_src_irr, const float* __restrict__ s_tgt_irr,
                                 const float* __restrict__ s_src_sol, const float* __restrict__ s_tgt_sol,
                                 const float* __restrict__ h_irr, const float* __restrict__ h_sol,
                                 float* __restrict__ out) {
    int wave = threadIdx.x >> 6;
    int lane = threadIdx.x & 63;
    int n = blockIdx.x * 4 + wave;     // grid 25000 exact
    int f = lane & 31;
    int half = lane >> 5;

    float res = branch_acc(n, n, lane, f, half, csr_tgt, offsets, counts,
                           s_src_irr, s_tgt_irr, h_irr);
    res += branch_acc(N_CELLS + n, n, lane, f, half, csr_tgt, offsets, counts,
                      s_src_sol, s_tgt_sol, h_sol);
    res = res > 0.f ? res : __expf(res) - 1.f;   // ELU
    if (half == 0) out[(size_t)n * FDIM + f] = res;
}

extern "C" void kernel_launch(void* const* d_in, const int* in_sizes, int n_in,
                              void* d_out, int out_size, void* d_ws, size_t ws_size,
                              hipStream_t stream) {
    const float* x = (const float*)d_in[0];
    const int* do_index = (const int*)d_in[1];
    const int* up_index = (const int*)d_in[2];
    const float* Wirr = (const float*)d_in[3];
    const float* Wsol = (const float*)d_in[4];
    const float* att_irr = (const float*)d_in[5];
    const float* att_sol = (const float*)d_in[6];
    float* out = (float*)d_out;

    // Workspace partition
    float* ws = (float*)d_ws;
    float* h_irr = ws;                                   // N*F
    float* h_sol = h_irr + (size_t)N_CELLS * FDIM;       // N*F
    float* s_src_irr = h_sol + (size_t)N_CELLS * FDIM;   // N
    float* s_tgt_irr = s_src_irr + N_CELLS;              // N
    float* s_src_sol = s_tgt_irr + N_CELLS;              // N
    float* s_tgt_sol = s_src_sol + N_CELLS;              // N
    int* counts = (int*)(s_tgt_sol + N_CELLS);           // NSEG
    int* offsets = counts + NSEG;                        // NSEG
    int* cursor = offsets + NSEG;                        // NSEG
    int* blksums = cursor + NSEG;                        // 128
    int* bin_cursor = blksums + 128;                     // NBIN*16 (64B-padded)
    int* csr_tgt = bin_cursor + NBIN * 16;               // 2*N_EDGES
    unsigned int* bin_buf = (unsigned int*)(csr_tgt + 2 * N_EDGES);  // 2*N_EDGES

    hipMemsetAsync(counts, 0, NSEG * sizeof(int), stream);

    // K1: fused h + scores + histogram
    hipLaunchKernelGGL(k_fused, dim3(EDGE_BLOCKS), dim3(256), 0, stream,
                       x, Wirr, Wsol, att_irr, att_sol, do_index, up_index,
                       h_irr, h_sol, s_src_irr, s_tgt_irr, s_src_sol, s_tgt_sol,
                       counts);

    // K2: exclusive scan of counts -> offsets (+cursor copy, +bin cursor init)
    hipLaunchKernelGGL(k_scan_a, dim3(NSCAN_BLOCKS), dim3(256), 0, stream,
                       counts, offsets, blksums);
    hipLaunchKernelGGL(k_scan_b, dim3(1), dim3(128), 0, stream, blksums);
    hipLaunchKernelGGL(k_scan_c, dim3((NSEG + 255) / 256), dim3(256), 0, stream,
                       offsets, cursor, blksums, bin_cursor);

    // K3a: bin edges by segment range (append-only coalesced writes)
    hipLaunchKernelGGL(k_bin, dim3(BIN_BLOCKS), dim3(256), 0, stream,
                       do_index, up_index, bin_cursor, bin_buf);

    // K3b: per-bin scatter into CSR (one bin per XCD, L2-resident working set)
    hipLaunchKernelGGL(k_scatter2, dim3(NBIN * P2_BLKS), dim3(256), 0, stream,
                       bin_buf, offsets, cursor, csr_tgt);

    // K4: per-node aggregate + ELU (1 wave/node, 4 waves/block -> exact grid)
    hipLaunchKernelGGL(k_node_aggregate, dim3(N_CELLS / 4), dim3(256), 0, stream,
                       csr_tgt, offsets, counts,
                       s_src_irr, s_tgt_irr, s_src_sol, s_tgt_sol,
                       h_irr, h_sol, out);
}

// Round 8
// 301.519 us; speedup vs baseline: 1.7569x; 1.5123x over previous
//
#include <hip/hip_runtime.h>
#include <math.h>

#define N_CELLS 100000
#define N_EDGES 1600000
#define FDIM 32
#define NEG_SLOPE 0.2f
#define NSEG (2 * N_CELLS)          // counts/offsets for both branches concatenated
#define SCAN_BLOCK 2048             // elements per scan block (256 thr x 8)
#define NSCAN_BLOCKS ((NSEG + SCAN_BLOCK - 1) / SCAN_BLOCK)   // 98
#define EDGE_BLOCKS ((2 * N_EDGES) / 256)                     // 12500 (exact)
#define NBIN 256
#define SEG_PER_BIN 782             // 256*782 = 200192 >= NSEG; local < 782 -> 10 bits
#define EPT 16                      // edges per thread in k_bin (4096/block -> 16/bin/block)
#define BIN_BLOCKS ((2 * N_EDGES + 256 * EPT - 1) / (256 * EPT))   // 782
#define LDSCAP 14000                // per-bin CSR slice capacity (expected ~12500, +13 sigma)

__device__ __forceinline__ float leaky(float v) {
    return v > 0.f ? v : NEG_SLOPE * v;
}

// Kernel 1 (fused): h = x@W (both branches), per-node attention scores,
// AND src histogram. Grid: 12500 x 256 exactly covers 100000 rows (8/block)
// and 3.2M edge slots.
__global__ void k_fused(const float* __restrict__ x,
                        const float* __restrict__ Wirr, const float* __restrict__ Wsol,
                        const float* __restrict__ att_irr, const float* __restrict__ att_sol,
                        const int* __restrict__ do_idx, const int* __restrict__ up_idx,
                        float* __restrict__ h_irr, float* __restrict__ h_sol,
                        float* __restrict__ s_src_irr, float* __restrict__ s_tgt_irr,
                        float* __restrict__ s_src_sol, float* __restrict__ s_tgt_sol,
                        int* __restrict__ counts) {
    __shared__ float sWirr[FDIM * FDIM], sWsol[FDIM * FDIM];
    __shared__ float sAi[2 * FDIM], sAs[2 * FDIM];
    int t = threadIdx.x;
    for (int i = t; i < FDIM * FDIM; i += 256) { sWirr[i] = Wirr[i]; sWsol[i] = Wsol[i]; }
    if (t < 2 * FDIM) { sAi[t] = att_irr[t]; sAs[t] = att_sol[t]; }
    __syncthreads();

    // --- histogram of src for both branches ---
    int tid = blockIdx.x * 256 + t;
    if (tid < N_EDGES) atomicAdd(&counts[do_idx[tid]], 1);
    else atomicAdd(&counts[N_CELLS + up_idx[tid - N_EDGES]], 1);

    // --- h + scores: one wave handles 2 rows (32 lanes per row) ---
    int wave = t >> 6, lane = t & 63, halfsel = lane >> 5, f = lane & 31;
    int row = blockIdx.x * 8 + wave * 2 + halfsel;
    const float* xr = x + (size_t)row * FDIM;
    float hi = 0.f, hs = 0.f;
#pragma unroll
    for (int k = 0; k < FDIM; ++k) {
        float xv = xr[k];
        hi += xv * sWirr[k * FDIM + f];
        hs += xv * sWsol[k * FDIM + f];
    }
    h_irr[(size_t)row * FDIM + f] = hi;
    h_sol[(size_t)row * FDIM + f] = hs;

    float pi0 = hi * sAi[f], pi1 = hi * sAi[FDIM + f];
    float ps0 = hs * sAs[f], ps1 = hs * sAs[FDIM + f];
#pragma unroll
    for (int m = 16; m >= 1; m >>= 1) {
        pi0 += __shfl_xor(pi0, m);
        pi1 += __shfl_xor(pi1, m);
        ps0 += __shfl_xor(ps0, m);
        ps1 += __shfl_xor(ps1, m);
    }
    if (f == 0) {
        s_src_irr[row] = pi0;
        s_tgt_irr[row] = pi1;
        s_src_sol[row] = ps0;
        s_tgt_sol[row] = ps1;
    }
}

// Scan a: per-block exclusive scan of counts (2048 elems/block) + block sums.
__global__ void k_scan_a(const int* __restrict__ counts, int* __restrict__ offsets,
                         int* __restrict__ blksums) {
    __shared__ int sdata[256];
    int t = threadIdx.x;
    int base = blockIdx.x * SCAN_BLOCK + t * 8;
    int v[8];
    int sum = 0;
#pragma unroll
    for (int j = 0; j < 8; ++j) {
        v[j] = (base + j < NSEG) ? counts[base + j] : 0;
        sum += v[j];
    }
    sdata[t] = sum;
    __syncthreads();
    for (int off = 1; off < 256; off <<= 1) {
        int xv = (t >= off) ? sdata[t - off] : 0;
        __syncthreads();
        sdata[t] += xv;
        __syncthreads();
    }
    int excl = (t == 0) ? 0 : sdata[t - 1];
    if (t == 255) blksums[blockIdx.x] = sdata[255];
    int run = excl;
#pragma unroll
    for (int j = 0; j < 8; ++j) {
        if (base + j < NSEG) offsets[base + j] = run;
        run += v[j];
    }
}

// Scan b: exclusive scan of the block sums (single block).
__global__ void k_scan_b(int* __restrict__ blksums) {
    __shared__ int s[128];
    int t = threadIdx.x;
    s[t] = (t < NSCAN_BLOCKS) ? blksums[t] : 0;
    __syncthreads();
    for (int off = 1; off < 128; off <<= 1) {
        int xv = (t >= off) ? s[t - off] : 0;
        __syncthreads();
        s[t] += xv;
        __syncthreads();
    }
    if (t < NSCAN_BLOCKS) blksums[t] = (t == 0) ? 0 : s[t - 1];
}

// Scan c: add block offsets; copy into cursor (fallback path only); init
// per-bin append cursors (padded: one counter per 64B line).
__global__ void k_scan_c(int* __restrict__ offsets, int* __restrict__ cursor,
                         const int* __restrict__ blksums, int* __restrict__ bin_cursor) {
    int i = blockIdx.x * 256 + threadIdx.x;
    if (i < NSEG) {
        int vv = offsets[i] + blksums[i >> 11];
        offsets[i] = vv;
        cursor[i] = vv;
        if (i % SEG_PER_BIN == 0) bin_cursor[(i / SEG_PER_BIN) * 16] = vv;
    }
}

// Pass 1 of the counting sort: append packed (local_seg,tgt) records to 256
// range-bins. Block-aggregated appends (LDS slot assignment + one global
// atomic per block per bin on line-padded cursors) make each bin an
// append-only log: lines fill densely in time and write back once.
// 16 edges/thread -> 16 records/bin/block (the density R6 validated).
__global__ void k_bin(const int* __restrict__ do_idx, const int* __restrict__ up_idx,
                      int* __restrict__ bin_cursor, unsigned int* __restrict__ bin_buf) {
    __shared__ unsigned int lcount[NBIN];
    __shared__ unsigned int lbase[NBIN];
    int t = threadIdx.x;
    if (t < NBIN) lcount[t] = 0u;
    __syncthreads();

    unsigned int recs[EPT];
    short binsv[EPT];
    unsigned short slots[EPT];
    int base = blockIdx.x * (256 * EPT);
#pragma unroll
    for (int j = 0; j < EPT; ++j) {
        int tid = base + j * 256 + t;     // coalesced per j
        binsv[j] = -1;
        if (tid < 2 * N_EDGES) {
            int seg, tg;
            if (tid < N_EDGES) {
                seg = do_idx[tid];
                tg = do_idx[N_EDGES + tid];
            } else {
                int e = tid - N_EDGES;
                seg = N_CELLS + up_idx[e];
                tg = up_idx[N_EDGES + e];
            }
            int bin = seg / SEG_PER_BIN;
            int local = seg - bin * SEG_PER_BIN;          // < 782 -> 10 bits
            recs[j] = ((unsigned int)local << 17) | (unsigned int)tg;  // tgt < 2^17
            binsv[j] = (short)bin;
            slots[j] = (unsigned short)atomicAdd(&lcount[bin], 1u);
        }
    }
    __syncthreads();
    if (t < NBIN) lbase[t] = (unsigned int)atomicAdd(&bin_cursor[t * 16], (int)lcount[t]);
    __syncthreads();
#pragma unroll
    for (int j = 0; j < EPT; ++j)
        if (binsv[j] >= 0)
            bin_buf[lbase[binsv[j]] + slots[j]] = recs[j];
}

// Pass 2: one workgroup per bin. Stream the bin slice (sequential read),
// permute it in LDS via LDS-atomic cursors, dump LDS -> csr_tgt sequentially.
// Every global write is coalesced and issued exactly once — no cache-
// residency assumption. Fallback (bin slice > LDSCAP, ~13 sigma, never
// expected on this data) scatters directly through the global cursor.
__global__ void k_scatter3(const unsigned int* __restrict__ bin_buf,
                           const int* __restrict__ offsets,
                           int* __restrict__ cursor, int* __restrict__ csr_tgt) {
    __shared__ int cur[SEG_PER_BIN];
    __shared__ int buf[LDSCAP];
    int bin = blockIdx.x;
    int t = threadIdx.x;
    int seg0 = bin * SEG_PER_BIN;
    int segN = NSEG - seg0;
    if (segN > SEG_PER_BIN) segN = SEG_PER_BIN;
    int start = offsets[seg0];
    int end = (seg0 + segN < NSEG) ? offsets[seg0 + segN] : 2 * N_EDGES;
    int len = end - start;
    if (len <= LDSCAP) {
        for (int i = t; i < segN; i += 256) cur[i] = offsets[seg0 + i] - start;
        __syncthreads();
        for (int idx = start + t; idx < end; idx += 256) {
            unsigned int rec = bin_buf[idx];
            int ls = (int)(rec >> 17);
            int pos = atomicAdd(&cur[ls], 1);
            buf[pos] = (int)(rec & 0x1FFFFu);
        }
        __syncthreads();
        for (int i = t; i < len; i += 256) csr_tgt[start + i] = buf[i];
    } else {
        for (int idx = start + t; idx < end; idx += 256) {
            unsigned int rec = bin_buf[idx];
            int seg = seg0 + (int)(rec >> 17);
            int pos = atomicAdd(&cursor[seg], 1);
            csr_tgt[pos] = (int)(rec & 0x1FFFFu);
        }
    }
}

// Per-branch accumulation with WAVE-UNIFORM control flow.
// Phase A: lane i holds edge i's (target, score); exact online max per chunk.
// Phase B: uniform loops; half-selection via shuffle SOURCE index (i+2j+half),
// so every __shfl executes with all 64 lanes active. Tail pairs clamp the
// source lane and zero the weight (predication, never divergent shuffles).
__device__ __forceinline__ float branch_acc(int seg, int n, int lane, int f, int half,
                                            const int* __restrict__ csr_tgt,
                                            const int* __restrict__ offsets,
                                            const int* __restrict__ counts,
                                            const float* __restrict__ s_src,
                                            const float* __restrict__ s_tgt,
                                            const float* __restrict__ h) {
    int beg = offsets[seg];
    int deg = counts[seg];
    float ssrc = s_src[n];
    float num = 0.f, den = 0.f, Mrun = -INFINITY;
    for (int base = 0; base < deg; base += 64) {
        int m = deg - base;
        if (m > 64) m = 64;
        int te = 0;
        float ev = -INFINITY;
        if (lane < m) {
            te = csr_tgt[beg + base + lane];
            ev = leaky(ssrc + s_tgt[te]);
        }
        // exact chunk max (allreduce over the wave)
        float cm = ev;
#pragma unroll
        for (int d = 32; d >= 1; d >>= 1) cm = fmaxf(cm, __shfl_xor(cm, d));
        float newM = fmaxf(Mrun, cm);
        float scale = __expf(Mrun - newM);   // 0 on first chunk (num=den=0)
        num *= scale;
        den *= scale;
        Mrun = newM;
        float we = __expf(ev - newM);        // 0 for lanes >= m (ev = -inf)

        int i = 0;
        for (; i + 15 < m; i += 16) {        // 8 independent gathers per lane
            int  t0 = __shfl(te, i +  0 + half), t1 = __shfl(te, i +  2 + half);
            int  t2 = __shfl(te, i +  4 + half), t3 = __shfl(te, i +  6 + half);
            int  t4 = __shfl(te, i +  8 + half), t5 = __shfl(te, i + 10 + half);
            int  t6 = __shfl(te, i + 12 + half), t7 = __shfl(te, i + 14 + half);
            float w0 = __shfl(we, i +  0 + half), w1 = __shfl(we, i +  2 + half);
            float w2 = __shfl(we, i +  4 + half), w3 = __shfl(we, i +  6 + half);
            float w4 = __shfl(we, i +  8 + half), w5 = __shfl(we, i + 10 + half);
            float w6 = __shfl(we, i + 12 + half), w7 = __shfl(we, i + 14 + half);
            float v0 = h[(size_t)t0 * FDIM + f], v1 = h[(size_t)t1 * FDIM + f];
            float v2 = h[(size_t)t2 * FDIM + f], v3 = h[(size_t)t3 * FDIM + f];
            float v4 = h[(size_t)t4 * FDIM + f], v5 = h[(size_t)t5 * FDIM + f];
            float v6 = h[(size_t)t6 * FDIM + f], v7 = h[(size_t)t7 * FDIM + f];
            num += w0 * v0 + w1 * v1 + w2 * v2 + w3 * v3;
            num += w4 * v4 + w5 * v5 + w6 * v6 + w7 * v7;
            den += w0 + w1 + w2 + w3 + w4 + w5 + w6 + w7;
        }
        for (; i + 7 < m; i += 8) {          // 4 independent gathers per lane
            int  t0 = __shfl(te, i + 0 + half), t1 = __shfl(te, i + 2 + half);
            int  t2 = __shfl(te, i + 4 + half), t3 = __shfl(te, i + 6 + half);
            float w0 = __shfl(we, i + 0 + half), w1 = __shfl(we, i + 2 + half);
            float w2 = __shfl(we, i + 4 + half), w3 = __shfl(we, i + 6 + half);
            float v0 = h[(size_t)t0 * FDIM + f], v1 = h[(size_t)t1 * FDIM + f];
            float v2 = h[(size_t)t2 * FDIM + f], v3 = h[(size_t)t3 * FDIM + f];
            num += w0 * v0 + w1 * v1 + w2 * v2 + w3 * v3;
            den += w0 + w1 + w2 + w3;
        }
        for (; i < m; i += 2) {              // uniform pair tail, clamped source
            int idx = i + half;
            int safe = (idx < m) ? idx : i;
            int tt = __shfl(te, safe);
            float ww = __shfl(we, safe);
            ww = (idx < m) ? ww : 0.f;
            num += ww * h[(size_t)tt * FDIM + f];
            den += ww;
        }
    }
    num += __shfl_xor(num, 32);
    den += __shfl_xor(den, 32);
    return num / (den + 1e-10f);
}

// Final aggregate: one 64-lane wave per node; ELU fused; single out write.
__global__ void k_node_aggregate(const int* __restrict__ csr_tgt,
                                 const int* __restrict__ offsets, const int* __restrict__ counts,
                                 const float* __restrict__ s_src_irr, const float* __restrict__ s_tgt_irr,
                                 const float* __restrict__ s_src_sol, const float* __restrict__ s_tgt_sol,
                                 const float* __restrict__ h_irr, const float* __restrict__ h_sol,
                                 float* __restrict__ out) {
    int wave = threadIdx.x >> 6;
    int lane = threadIdx.x & 63;
    int n = blockIdx.x * 4 + wave;     // grid 25000 exact
    int f = lane & 31;
    int half = lane >> 5;

    float res = branch_acc(n, n, lane, f, half, csr_tgt, offsets, counts,
                           s_src_irr, s_tgt_irr, h_irr);
    res += branch_acc(N_CELLS + n, n, lane, f, half, csr_tgt, offsets, counts,
                      s_src_sol, s_tgt_sol, h_sol);
    res = res > 0.f ? res : __expf(res) - 1.f;   // ELU
    if (half == 0) out[(size_t)n * FDIM + f] = res;
}

extern "C" void kernel_launch(void* const* d_in, const int* in_sizes, int n_in,
                              void* d_out, int out_size, void* d_ws, size_t ws_size,
                              hipStream_t stream) {
    const float* x = (const float*)d_in[0];
    const int* do_index = (const int*)d_in[1];
    const int* up_index = (const int*)d_in[2];
    const float* Wirr = (const float*)d_in[3];
    const float* Wsol = (const float*)d_in[4];
    const float* att_irr = (const float*)d_in[5];
    const float* att_sol = (const float*)d_in[6];
    float* out = (float*)d_out;

    // Workspace partition
    float* ws = (float*)d_ws;
    float* h_irr = ws;                                   // N*F
    float* h_sol = h_irr + (size_t)N_CELLS * FDIM;       // N*F
    float* s_src_irr = h_sol + (size_t)N_CELLS * FDIM;   // N
    float* s_tgt_irr = s_src_irr + N_CELLS;              // N
    float* s_src_sol = s_tgt_irr + N_CELLS;              // N
    float* s_tgt_sol = s_src_sol + N_CELLS;              // N
    int* counts = (int*)(s_tgt_sol + N_CELLS);           // NSEG
    int* offsets = counts + NSEG;                        // NSEG
    int* cursor = offsets + NSEG;                        // NSEG
    int* blksums = cursor + NSEG;                        // 128
    int* bin_cursor = blksums + 128;                     // NBIN*16 (64B-padded)
    int* csr_tgt = bin_cursor + NBIN * 16;               // 2*N_EDGES
    unsigned int* bin_buf = (unsigned int*)(csr_tgt + 2 * N_EDGES);  // 2*N_EDGES

    hipMemsetAsync(counts, 0, NSEG * sizeof(int), stream);

    // K1: fused h + scores + histogram
    hipLaunchKernelGGL(k_fused, dim3(EDGE_BLOCKS), dim3(256), 0, stream,
                       x, Wirr, Wsol, att_irr, att_sol, do_index, up_index,
                       h_irr, h_sol, s_src_irr, s_tgt_irr, s_src_sol, s_tgt_sol,
                       counts);

    // K2: exclusive scan of counts -> offsets (+cursor copy, +bin cursor init)
    hipLaunchKernelGGL(k_scan_a, dim3(NSCAN_BLOCKS), dim3(256), 0, stream,
                       counts, offsets, blksums);
    hipLaunchKernelGGL(k_scan_b, dim3(1), dim3(128), 0, stream, blksums);
    hipLaunchKernelGGL(k_scan_c, dim3((NSEG + 255) / 256), dim3(256), 0, stream,
                       offsets, cursor, blksums, bin_cursor);

    // K3a: bin edges by segment range (append-only coalesced writes)
    hipLaunchKernelGGL(k_bin, dim3(BIN_BLOCKS), dim3(256), 0, stream,
                       do_index, up_index, bin_cursor, bin_buf);

    // K3b: per-bin LDS permute -> fully coalesced CSR writes
    hipLaunchKernelGGL(k_scatter3, dim3(NBIN), dim3(256), 0, stream,
                       bin_buf, offsets, cursor, csr_tgt);

    // K4: per-node aggregate + ELU (1 wave/node, 4 waves/block -> exact grid)
    hipLaunchKernelGGL(k_node_aggregate, dim3(N_CELLS / 4), dim3(256), 0, stream,
                       csr_tgt, offsets, counts,
                       s_src_irr, s_tgt_irr, s_src_sol, s_tgt_sol,
                       h_irr, h_sol, out);
}

// Round 9
// 204.905 us; speedup vs baseline: 2.5853x; 1.4715x over previous
//
#include <hip/hip_runtime.h>
#include <math.h>

#define N_CELLS 100000
#define N_EDGES 1600000
#define FDIM 32
#define NEG_SLOPE 0.2f
#define NSEG (2 * N_CELLS)          // segments: both branches concatenated
#define NBIN 250
#define SEG_PER_BIN 800             // 250*800 = 200000 == NSEG exactly; local < 800 -> 10 bits
#define BIN_STRIDE 16000            // fixed slack region per bin (expected 12800, +25 sigma)
#define LDSCAP 14336                // LDS permute capacity (expected 12800, +12 sigma; fallback beyond)
#define EPT 16                      // edges per thread in k_bin
#define BIN_BLOCKS ((2 * N_EDGES + 256 * EPT - 1) / (256 * EPT))   // 782

__device__ __forceinline__ float leaky(float v) {
    return v > 0.f ? v : NEG_SLOPE * v;
}

// Kernel 1: h = x@W (both branches) + per-node attention scores. Pure
// streaming: reads x once, writes h/s coalesced. No atomics, no edges.
__global__ void k_fused(const float* __restrict__ x,
                        const float* __restrict__ Wirr, const float* __restrict__ Wsol,
                        const float* __restrict__ att_irr, const float* __restrict__ att_sol,
                        float* __restrict__ h_irr, float* __restrict__ h_sol,
                        float* __restrict__ s_src_irr, float* __restrict__ s_tgt_irr,
                        float* __restrict__ s_src_sol, float* __restrict__ s_tgt_sol) {
    __shared__ float sWirr[FDIM * FDIM], sWsol[FDIM * FDIM];
    __shared__ float sAi[2 * FDIM], sAs[2 * FDIM];
    int t = threadIdx.x;
    for (int i = t; i < FDIM * FDIM; i += 256) { sWirr[i] = Wirr[i]; sWsol[i] = Wsol[i]; }
    if (t < 2 * FDIM) { sAi[t] = att_irr[t]; sAs[t] = att_sol[t]; }
    __syncthreads();

    int wave = t >> 6, lane = t & 63, halfsel = lane >> 5, f = lane & 31;
    int row = blockIdx.x * 8 + wave * 2 + halfsel;    // grid 12500 x 8 rows exact
    const float* xr = x + (size_t)row * FDIM;
    float hi = 0.f, hs = 0.f;
#pragma unroll
    for (int k = 0; k < FDIM; ++k) {
        float xv = xr[k];
        hi += xv * sWirr[k * FDIM + f];
        hs += xv * sWsol[k * FDIM + f];
    }
    h_irr[(size_t)row * FDIM + f] = hi;
    h_sol[(size_t)row * FDIM + f] = hs;

    float pi0 = hi * sAi[f], pi1 = hi * sAi[FDIM + f];
    float ps0 = hs * sAs[f], ps1 = hs * sAs[FDIM + f];
#pragma unroll
    for (int m = 16; m >= 1; m >>= 1) {
        pi0 += __shfl_xor(pi0, m);
        pi1 += __shfl_xor(pi1, m);
        ps0 += __shfl_xor(ps0, m);
        ps1 += __shfl_xor(ps1, m);
    }
    if (f == 0) {
        s_src_irr[row] = pi0;
        s_tgt_irr[row] = pi1;
        s_src_sol[row] = ps0;
        s_tgt_sol[row] = ps1;
    }
}

// k_bin: append packed (local_seg,tgt) records to 250 fixed-stride bins.
// Block-aggregated appends (LDS slot assignment + one global atomic per
// block per bin on line-padded cursors): each bin is an append-only log,
// lines fill densely in time and write back once. No pre-sizing histogram
// needed — BIN_STRIDE slack is +25 sigma over the expected bin length.
__global__ void k_bin(const int* __restrict__ do_idx, const int* __restrict__ up_idx,
                      int* __restrict__ bin_cursor, unsigned int* __restrict__ bin_buf) {
    __shared__ unsigned int lcount[NBIN];
    __shared__ unsigned int lbase[NBIN];
    int t = threadIdx.x;
    for (int i = t; i < NBIN; i += 256) lcount[i] = 0u;
    __syncthreads();

    unsigned int recs[EPT];
    short binsv[EPT];
    unsigned short slots[EPT];
    int base = blockIdx.x * (256 * EPT);
#pragma unroll
    for (int j = 0; j < EPT; ++j) {
        int tid = base + j * 256 + t;     // coalesced per j
        binsv[j] = -1;
        if (tid < 2 * N_EDGES) {
            int seg, tg;
            if (tid < N_EDGES) {
                seg = do_idx[tid];
                tg = do_idx[N_EDGES + tid];
            } else {
                int e = tid - N_EDGES;
                seg = N_CELLS + up_idx[e];
                tg = up_idx[N_EDGES + e];
            }
            int bin = seg / SEG_PER_BIN;
            int local = seg - bin * SEG_PER_BIN;          // < 800 -> 10 bits
            recs[j] = ((unsigned int)local << 17) | (unsigned int)tg;  // tgt < 2^17
            binsv[j] = (short)bin;
            slots[j] = (unsigned short)atomicAdd(&lcount[bin], 1u);
        }
    }
    __syncthreads();
    for (int i = t; i < NBIN; i += 256)
        lbase[i] = (unsigned int)(i * BIN_STRIDE) +
                   (unsigned int)atomicAdd(&bin_cursor[i * 16], (int)lcount[i]);
    __syncthreads();
#pragma unroll
    for (int j = 0; j < EPT; ++j)
        if (binsv[j] >= 0)
            bin_buf[lbase[binsv[j]] + slots[j]] = recs[j];
}

// k_binscan: exclusive scan of the 250 bin lengths (single block).
__global__ void k_binscan(const int* __restrict__ bin_cursor, int* __restrict__ bin_start) {
    __shared__ int s[256];
    int t = threadIdx.x;
    int v = (t < NBIN) ? bin_cursor[t * 16] : 0;
    s[t] = v;
    __syncthreads();
    for (int off = 1; off < 256; off <<= 1) {
        int xv = (t >= off) ? s[t - off] : 0;
        __syncthreads();
        s[t] += xv;
        __syncthreads();
    }
    if (t < NBIN) bin_start[t] = s[t] - v;   // exclusive prefix
}

// k_scatter3: one workgroup per bin. Pass A streams the bin's records and
// LDS-histograms the 800 local segments; LDS exclusive scan gives local
// offsets; counts/offsets written coalesced. Pass B permutes records into
// an LDS buffer via LDS cursors, then dumps LDS -> csr_tgt sequentially:
// every global write coalesced, written exactly once. Fallback for a
// freak oversized bin scatters directly (correct, uncoalesced).
__global__ void k_scatter3(const unsigned int* __restrict__ bin_buf,
                           const int* __restrict__ bin_cursor, const int* __restrict__ bin_start,
                           int* __restrict__ offsets, int* __restrict__ counts,
                           int* __restrict__ csr_tgt) {
    __shared__ int hist[SEG_PER_BIN];
    __shared__ int lofs[SEG_PER_BIN];
    __shared__ int ss[256];
    __shared__ int buf[LDSCAP];
    int bin = blockIdx.x;
    int t = threadIdx.x;
    int len = bin_cursor[bin * 16];
    int rbase = bin * BIN_STRIDE;
    int outstart = bin_start[bin];
    int seg0 = bin * SEG_PER_BIN;

    for (int i = t; i < SEG_PER_BIN; i += 256) hist[i] = 0;
    __syncthreads();
    for (int idx = t; idx < len; idx += 256)
        atomicAdd(&hist[bin_buf[rbase + idx] >> 17], 1);
    __syncthreads();

    // exclusive scan of hist[0..800): 4 elems/thread + block scan of sums
    int b4 = t * 4;
    int v0 = 0, v1 = 0, v2 = 0, v3 = 0, sum = 0;
    if (b4 < SEG_PER_BIN) {
        v0 = hist[b4]; v1 = hist[b4 + 1]; v2 = hist[b4 + 2]; v3 = hist[b4 + 3];
        sum = v0 + v1 + v2 + v3;
    }
    ss[t] = sum;
    __syncthreads();
    for (int off = 1; off < 256; off <<= 1) {
        int xv = (t >= off) ? ss[t - off] : 0;
        __syncthreads();
        ss[t] += xv;
        __syncthreads();
    }
    int excl = (t == 0) ? 0 : ss[t - 1];
    if (b4 < SEG_PER_BIN) {
        lofs[b4] = excl;
        lofs[b4 + 1] = excl + v0;
        lofs[b4 + 2] = excl + v0 + v1;
        lofs[b4 + 3] = excl + v0 + v1 + v2;
    }
    __syncthreads();

    // counts / offsets (coalesced; 250*800 == NSEG exactly)
    for (int i = t; i < SEG_PER_BIN; i += 256) {
        offsets[seg0 + i] = outstart + lofs[i];
        counts[seg0 + i] = hist[i];
    }
    __syncthreads();

    if (len <= LDSCAP) {
        for (int idx = t; idx < len; idx += 256) {
            unsigned int rec = bin_buf[rbase + idx];
            int pos = atomicAdd(&lofs[rec >> 17], 1);
            buf[pos] = (int)(rec & 0x1FFFFu);
        }
        __syncthreads();
        for (int i = t; i < len; i += 256) csr_tgt[outstart + i] = buf[i];
    } else {
        for (int idx = t; idx < len; idx += 256) {
            unsigned int rec = bin_buf[rbase + idx];
            int pos = outstart + atomicAdd(&lofs[rec >> 17], 1);
            csr_tgt[pos] = (int)(rec & 0x1FFFFu);
        }
    }
}

// Per-branch accumulation with WAVE-UNIFORM control flow.
// Phase A: lane i holds edge i's (target, score); exact online max per chunk.
// Phase B: uniform loops; half-selection via shuffle SOURCE index (i+2j+half),
// so every __shfl executes with all 64 lanes active. Tail pairs clamp the
// source lane and zero the weight (predication, never divergent shuffles).
__device__ __forceinline__ float branch_acc(int seg, int n, int lane, int f, int half,
                                            const int* __restrict__ csr_tgt,
                                            const int* __restrict__ offsets,
                                            const int* __restrict__ counts,
                                            const float* __restrict__ s_src,
                                            const float* __restrict__ s_tgt,
                                            const float* __restrict__ h) {
    int beg = offsets[seg];
    int deg = counts[seg];
    float ssrc = s_src[n];
    float num = 0.f, den = 0.f, Mrun = -INFINITY;
    for (int base = 0; base < deg; base += 64) {
        int m = deg - base;
        if (m > 64) m = 64;
        int te = 0;
        float ev = -INFINITY;
        if (lane < m) {
            te = csr_tgt[beg + base + lane];
            ev = leaky(ssrc + s_tgt[te]);
        }
        // exact chunk max (allreduce over the wave)
        float cm = ev;
#pragma unroll
        for (int d = 32; d >= 1; d >>= 1) cm = fmaxf(cm, __shfl_xor(cm, d));
        float newM = fmaxf(Mrun, cm);
        float scale = __expf(Mrun - newM);   // 0 on first chunk (num=den=0)
        num *= scale;
        den *= scale;
        Mrun = newM;
        float we = __expf(ev - newM);        // 0 for lanes >= m (ev = -inf)

        int i = 0;
        for (; i + 15 < m; i += 16) {        // 8 independent gathers per lane
            int  t0 = __shfl(te, i +  0 + half), t1 = __shfl(te, i +  2 + half);
            int  t2 = __shfl(te, i +  4 + half), t3 = __shfl(te, i +  6 + half);
            int  t4 = __shfl(te, i +  8 + half), t5 = __shfl(te, i + 10 + half);
            int  t6 = __shfl(te, i + 12 + half), t7 = __shfl(te, i + 14 + half);
            float w0 = __shfl(we, i +  0 + half), w1 = __shfl(we, i +  2 + half);
            float w2 = __shfl(we, i +  4 + half), w3 = __shfl(we, i +  6 + half);
            float w4 = __shfl(we, i +  8 + half), w5 = __shfl(we, i + 10 + half);
            float w6 = __shfl(we, i + 12 + half), w7 = __shfl(we, i + 14 + half);
            float v0 = h[(size_t)t0 * FDIM + f], v1 = h[(size_t)t1 * FDIM + f];
            float v2 = h[(size_t)t2 * FDIM + f], v3 = h[(size_t)t3 * FDIM + f];
            float v4 = h[(size_t)t4 * FDIM + f], v5 = h[(size_t)t5 * FDIM + f];
            float v6 = h[(size_t)t6 * FDIM + f], v7 = h[(size_t)t7 * FDIM + f];
            num += w0 * v0 + w1 * v1 + w2 * v2 + w3 * v3;
            num += w4 * v4 + w5 * v5 + w6 * v6 + w7 * v7;
            den += w0 + w1 + w2 + w3 + w4 + w5 + w6 + w7;
        }
        for (; i + 7 < m; i += 8) {          // 4 independent gathers per lane
            int  t0 = __shfl(te, i + 0 + half), t1 = __shfl(te, i + 2 + half);
            int  t2 = __shfl(te, i + 4 + half), t3 = __shfl(te, i + 6 + half);
            float w0 = __shfl(we, i + 0 + half), w1 = __shfl(we, i + 2 + half);
            float w2 = __shfl(we, i + 4 + half), w3 = __shfl(we, i + 6 + half);
            float v0 = h[(size_t)t0 * FDIM + f], v1 = h[(size_t)t1 * FDIM + f];
            float v2 = h[(size_t)t2 * FDIM + f], v3 = h[(size_t)t3 * FDIM + f];
            num += w0 * v0 + w1 * v1 + w2 * v2 + w3 * v3;
            den += w0 + w1 + w2 + w3;
        }
        for (; i < m; i += 2) {              // uniform pair tail, clamped source
            int idx = i + half;
            int safe = (idx < m) ? idx : i;
            int tt = __shfl(te, safe);
            float ww = __shfl(we, safe);
            ww = (idx < m) ? ww : 0.f;
            num += ww * h[(size_t)tt * FDIM + f];
            den += ww;
        }
    }
    num += __shfl_xor(num, 32);
    den += __shfl_xor(den, 32);
    return num / (den + 1e-10f);
}

// Final aggregate: one 64-lane wave per node; ELU fused; single out write.
__global__ void k_node_aggregate(const int* __restrict__ csr_tgt,
                                 const int* __restrict__ offsets, const int* __restrict__ counts,
                                 const float* __restrict__ s_src_irr, const float* __restrict__ s_tgt_irr,
                                 const float* __restrict__ s_src_sol, const float* __restrict__ s_tgt_sol,
                                 const float* __restrict__ h_irr, const float* __restrict__ h_sol,
                                 float* __restrict__ out) {
    int wave = threadIdx.x >> 6;
    int lane = threadIdx.x & 63;
    int n = blockIdx.x * 4 + wave;     // grid 25000 exact
    int f = lane & 31;
    int half = lane >> 5;

    float res = branch_acc(n, n, lane, f, half, csr_tgt, offsets, counts,
                           s_src_irr, s_tgt_irr, h_irr);
    res += branch_acc(N_CELLS + n, n, lane, f, half, csr_tgt, offsets, counts,
                      s_src_sol, s_tgt_sol, h_sol);
    res = res > 0.f ? res : __expf(res) - 1.f;   // ELU
    if (half == 0) out[(size_t)n * FDIM + f] = res;
}

extern "C" void kernel_launch(void* const* d_in, const int* in_sizes, int n_in,
                              void* d_out, int out_size, void* d_ws, size_t ws_size,
                              hipStream_t stream) {
    const float* x = (const float*)d_in[0];
    const int* do_index = (const int*)d_in[1];
    const int* up_index = (const int*)d_in[2];
    const float* Wirr = (const float*)d_in[3];
    const float* Wsol = (const float*)d_in[4];
    const float* att_irr = (const float*)d_in[5];
    const float* att_sol = (const float*)d_in[6];
    float* out = (float*)d_out;

    // Workspace partition
    float* ws = (float*)d_ws;
    float* h_irr = ws;                                   // N*F
    float* h_sol = h_irr + (size_t)N_CELLS * FDIM;       // N*F
    float* s_src_irr = h_sol + (size_t)N_CELLS * FDIM;   // N
    float* s_tgt_irr = s_src_irr + N_CELLS;              // N
    float* s_src_sol = s_tgt_irr + N_CELLS;              // N
    float* s_tgt_sol = s_src_sol + N_CELLS;              // N
    int* counts = (int*)(s_tgt_sol + N_CELLS);           // NSEG
    int* offsets = counts + NSEG;                        // NSEG
    int* bin_cursor = offsets + NSEG;                    // NBIN*16 (64B-padded)
    int* bin_start = bin_cursor + NBIN * 16;             // NBIN
    int* csr_tgt = bin_start + NBIN + 64;                // 2*N_EDGES
    unsigned int* bin_buf = (unsigned int*)(csr_tgt + 2 * N_EDGES);  // NBIN*BIN_STRIDE

    hipMemsetAsync(bin_cursor, 0, NBIN * 16 * sizeof(int), stream);

    // K1: h + scores (pure streaming)
    hipLaunchKernelGGL(k_fused, dim3(N_CELLS / 8), dim3(256), 0, stream,
                       x, Wirr, Wsol, att_irr, att_sol,
                       h_irr, h_sol, s_src_irr, s_tgt_irr, s_src_sol, s_tgt_sol);

    // K2: bin edges into fixed-stride append logs
    hipLaunchKernelGGL(k_bin, dim3(BIN_BLOCKS), dim3(256), 0, stream,
                       do_index, up_index, bin_cursor, bin_buf);

    // K3: scan of bin lengths
    hipLaunchKernelGGL(k_binscan, dim3(1), dim3(256), 0, stream, bin_cursor, bin_start);

    // K4: per-bin LDS histogram + scan + permute -> counts/offsets/csr_tgt
    hipLaunchKernelGGL(k_scatter3, dim3(NBIN), dim3(256), 0, stream,
                       bin_buf, bin_cursor, bin_start, offsets, counts, csr_tgt);

    // K5: per-node aggregate + ELU (1 wave/node, 4 waves/block -> exact grid)
    hipLaunchKernelGGL(k_node_aggregate, dim3(N_CELLS / 4), dim3(256), 0, stream,
                       csr_tgt, offsets, counts,
                       s_src_irr, s_tgt_irr, s_src_sol, s_tgt_sol,
                       h_irr, h_sol, out);
}

// Round 10
// 192.455 us; speedup vs baseline: 2.7525x; 1.0647x over previous
//
#include <hip/hip_runtime.h>
#include <math.h>

#define N_CELLS 100000
#define N_EDGES 1600000
#define FDIM 32
#define NEG_SLOPE 0.2f
#define NSEG (2 * N_CELLS)          // segments: both branches concatenated
#define NBIN 250
#define SEG_PER_BIN 800             // 250*800 = 200000 == NSEG exactly; local < 800 -> 10 bits
#define BIN_STRIDE 16000            // fixed slack region per bin (expected 12800, +25 sigma)
#define LDSCAP 14336                // LDS permute capacity (expected 12800, +12 sigma; fallback beyond)
#define EPT 16                      // edges per thread in k_bin
#define BIN_BLOCKS ((2 * N_EDGES + 256 * EPT - 1) / (256 * EPT))   // 782

__device__ __forceinline__ float leaky(float v) {
    return v > 0.f ? v : NEG_SLOPE * v;
}
// RNE f32 -> bf16 (values are normal floats; no NaN handling needed)
__device__ __forceinline__ unsigned short f32_to_bf16(float f) {
    unsigned int b = __float_as_uint(f);
    unsigned int r = b + 0x7FFFu + ((b >> 16) & 1u);
    return (unsigned short)(r >> 16);
}

// Kernel 1: h = x@W (both branches, stored bf16) + per-node attention scores.
// Pure streaming: reads x once, writes h16/s coalesced. No atomics, no edges.
__global__ void k_fused(const float* __restrict__ x,
                        const float* __restrict__ Wirr, const float* __restrict__ Wsol,
                        const float* __restrict__ att_irr, const float* __restrict__ att_sol,
                        unsigned short* __restrict__ h16_irr, unsigned short* __restrict__ h16_sol,
                        float* __restrict__ s_src_irr, float* __restrict__ s_tgt_irr,
                        float* __restrict__ s_src_sol, float* __restrict__ s_tgt_sol) {
    __shared__ float sWirr[FDIM * FDIM], sWsol[FDIM * FDIM];
    __shared__ float sAi[2 * FDIM], sAs[2 * FDIM];
    int t = threadIdx.x;
    for (int i = t; i < FDIM * FDIM; i += 256) { sWirr[i] = Wirr[i]; sWsol[i] = Wsol[i]; }
    if (t < 2 * FDIM) { sAi[t] = att_irr[t]; sAs[t] = att_sol[t]; }
    __syncthreads();

    int wave = t >> 6, lane = t & 63, halfsel = lane >> 5, f = lane & 31;
    int row = blockIdx.x * 8 + wave * 2 + halfsel;    // grid 12500 x 8 rows exact
    const float* xr = x + (size_t)row * FDIM;
    float hi = 0.f, hs = 0.f;
#pragma unroll
    for (int k = 0; k < FDIM; ++k) {
        float xv = xr[k];
        hi += xv * sWirr[k * FDIM + f];
        hs += xv * sWsol[k * FDIM + f];
    }
    h16_irr[(size_t)row * FDIM + f] = f32_to_bf16(hi);
    h16_sol[(size_t)row * FDIM + f] = f32_to_bf16(hs);

    float pi0 = hi * sAi[f], pi1 = hi * sAi[FDIM + f];
    float ps0 = hs * sAs[f], ps1 = hs * sAs[FDIM + f];
#pragma unroll
    for (int m = 16; m >= 1; m >>= 1) {
        pi0 += __shfl_xor(pi0, m);
        pi1 += __shfl_xor(pi1, m);
        ps0 += __shfl_xor(ps0, m);
        ps1 += __shfl_xor(ps1, m);
    }
    if (f == 0) {
        s_src_irr[row] = pi0;
        s_tgt_irr[row] = pi1;
        s_src_sol[row] = ps0;
        s_tgt_sol[row] = ps1;
    }
}

// k_bin: append packed (local_seg,tgt) records to 250 fixed-stride bins.
// Block-aggregated appends (LDS slot assignment + one global atomic per
// block per bin on line-padded cursors): each bin is an append-only log,
// lines fill densely in time and write back once.
__global__ void k_bin(const int* __restrict__ do_idx, const int* __restrict__ up_idx,
                      int* __restrict__ bin_cursor, unsigned int* __restrict__ bin_buf) {
    __shared__ unsigned int lcount[NBIN];
    __shared__ unsigned int lbase[NBIN];
    int t = threadIdx.x;
    for (int i = t; i < NBIN; i += 256) lcount[i] = 0u;
    __syncthreads();

    unsigned int recs[EPT];
    short binsv[EPT];
    unsigned short slots[EPT];
    int base = blockIdx.x * (256 * EPT);
#pragma unroll
    for (int j = 0; j < EPT; ++j) {
        int tid = base + j * 256 + t;     // coalesced per j
        binsv[j] = -1;
        if (tid < 2 * N_EDGES) {
            int seg, tg;
            if (tid < N_EDGES) {
                seg = do_idx[tid];
                tg = do_idx[N_EDGES + tid];
            } else {
                int e = tid - N_EDGES;
                seg = N_CELLS + up_idx[e];
                tg = up_idx[N_EDGES + e];
            }
            int bin = seg / SEG_PER_BIN;
            int local = seg - bin * SEG_PER_BIN;          // < 800 -> 10 bits
            recs[j] = ((unsigned int)local << 17) | (unsigned int)tg;  // tgt < 2^17
            binsv[j] = (short)bin;
            slots[j] = (unsigned short)atomicAdd(&lcount[bin], 1u);
        }
    }
    __syncthreads();
    for (int i = t; i < NBIN; i += 256)
        lbase[i] = (unsigned int)(i * BIN_STRIDE) +
                   (unsigned int)atomicAdd(&bin_cursor[i * 16], (int)lcount[i]);
    __syncthreads();
#pragma unroll
    for (int j = 0; j < EPT; ++j)
        if (binsv[j] >= 0)
            bin_buf[lbase[binsv[j]] + slots[j]] = recs[j];
}

// k_scatter3: one workgroup per bin. Computes its own output prefix (scan of
// the 250 bin lengths in LDS), streams the bin's records, LDS-histograms the
// 800 local segments, LDS-scans for local offsets, writes counts/offsets
// coalesced, then permutes records into LDS and dumps -> csr_tgt
// sequentially: every global write coalesced, written exactly once.
__global__ void k_scatter3(const unsigned int* __restrict__ bin_buf,
                           const int* __restrict__ bin_cursor,
                           int* __restrict__ offsets, int* __restrict__ counts,
                           int* __restrict__ csr_tgt) {
    __shared__ int hist[SEG_PER_BIN];
    __shared__ int lofs[SEG_PER_BIN];
    __shared__ int ss[256];
    __shared__ int buf[LDSCAP];
    int bin = blockIdx.x;
    int t = threadIdx.x;
    int len = bin_cursor[bin * 16];
    int rbase = bin * BIN_STRIDE;
    int seg0 = bin * SEG_PER_BIN;

    // exclusive prefix of bin lengths -> outstart
    int partial = 0;
    for (int i = t; i < bin; i += 256) partial += bin_cursor[i * 16];
    ss[t] = partial;
    __syncthreads();
    for (int off = 128; off > 0; off >>= 1) {
        if (t < off) ss[t] += ss[t + off];
        __syncthreads();
    }
    int outstart = ss[0];
    __syncthreads();   // ss reused below

    for (int i = t; i < SEG_PER_BIN; i += 256) hist[i] = 0;
    __syncthreads();
    for (int idx = t; idx < len; idx += 256)
        atomicAdd(&hist[bin_buf[rbase + idx] >> 17], 1);
    __syncthreads();

    // exclusive scan of hist[0..800): 4 elems/thread + block scan of sums
    int b4 = t * 4;
    int v0 = 0, v1 = 0, v2 = 0, v3 = 0, sum = 0;
    if (b4 < SEG_PER_BIN) {
        v0 = hist[b4]; v1 = hist[b4 + 1]; v2 = hist[b4 + 2]; v3 = hist[b4 + 3];
        sum = v0 + v1 + v2 + v3;
    }
    ss[t] = sum;
    __syncthreads();
    for (int off = 1; off < 256; off <<= 1) {
        int xv = (t >= off) ? ss[t - off] : 0;
        __syncthreads();
        ss[t] += xv;
        __syncthreads();
    }
    int excl = (t == 0) ? 0 : ss[t - 1];
    if (b4 < SEG_PER_BIN) {
        lofs[b4] = excl;
        lofs[b4 + 1] = excl + v0;
        lofs[b4 + 2] = excl + v0 + v1;
        lofs[b4 + 3] = excl + v0 + v1 + v2;
    }
    __syncthreads();

    // counts / offsets (coalesced; 250*800 == NSEG exactly)
    for (int i = t; i < SEG_PER_BIN; i += 256) {
        offsets[seg0 + i] = outstart + lofs[i];
        counts[seg0 + i] = hist[i];
    }
    __syncthreads();

    if (len <= LDSCAP) {
        for (int idx = t; idx < len; idx += 256) {
            unsigned int rec = bin_buf[rbase + idx];
            int pos = atomicAdd(&lofs[rec >> 17], 1);
            buf[pos] = (int)(rec & 0x1FFFFu);
        }
        __syncthreads();
        for (int i = t; i < len; i += 256) csr_tgt[outstart + i] = buf[i];
    } else {
        for (int idx = t; idx < len; idx += 256) {
            unsigned int rec = bin_buf[rbase + idx];
            int pos = outstart + atomicAdd(&lofs[rec >> 17], 1);
            csr_tgt[pos] = (int)(rec & 0x1FFFFu);
        }
    }
}

// Per-branch accumulation, quarter scheme, WAVE-UNIFORM control flow.
// Phase A: lane i holds edge i's (target, score); exact online max per chunk.
// Phase B: 4 edges processed concurrently (q = lane>>4 selects the edge,
// f2 = lane&15 selects a packed bf16 feature pair); shuffle SOURCE index
// carries the quarter, so every __shfl runs with all 64 lanes active.
// Tail clamps the source lane and zeroes the weight (predication only).
__device__ __forceinline__ float2 branch_acc(int seg, int n, int lane, int f2, int q,
                                             const int* __restrict__ csr_tgt,
                                             const int* __restrict__ offsets,
                                             const int* __restrict__ counts,
                                             const float* __restrict__ s_src,
                                             const float* __restrict__ s_tgt,
                                             const unsigned short* __restrict__ h16) {
    int beg = offsets[seg];
    int deg = counts[seg];
    float ssrc = s_src[n];
    float num0 = 0.f, num1 = 0.f, den = 0.f, Mrun = -INFINITY;
    for (int base = 0; base < deg; base += 64) {
        int m = deg - base;
        if (m > 64) m = 64;
        int te = 0;
        float ev = -INFINITY;
        if (lane < m) {
            te = csr_tgt[beg + base + lane];
            ev = leaky(ssrc + s_tgt[te]);
        }
        float cm = ev;
#pragma unroll
        for (int d = 32; d >= 1; d >>= 1) cm = fmaxf(cm, __shfl_xor(cm, d));
        float newM = fmaxf(Mrun, cm);
        float scale = __expf(Mrun - newM);   // 0 on first chunk (num=den=0)
        num0 *= scale;
        num1 *= scale;
        den *= scale;
        Mrun = newM;
        float we = __expf(ev - newM);        // 0 for lanes >= m (ev = -inf)

#define GATHER_STEP(IDX)                                                        \
        {                                                                       \
            int  tt = __shfl(te, (IDX));                                        \
            float ww = __shfl(we, (IDX));                                       \
            unsigned int u = *(const unsigned int*)(h16 + ((size_t)tt << 5) + (f2 << 1)); \
            float lo = __uint_as_float(u << 16);                                \
            float hi = __uint_as_float(u & 0xFFFF0000u);                        \
            num0 += ww * lo;                                                    \
            num1 += ww * hi;                                                    \
            den += ww;                                                          \
        }

        int i = 0;
        for (; i + 31 < m; i += 32) {        // 8 independent gathers per lane
            GATHER_STEP(i + 0 + q)  GATHER_STEP(i + 4 + q)
            GATHER_STEP(i + 8 + q)  GATHER_STEP(i + 12 + q)
            GATHER_STEP(i + 16 + q) GATHER_STEP(i + 20 + q)
            GATHER_STEP(i + 24 + q) GATHER_STEP(i + 28 + q)
        }
        for (; i + 7 < m; i += 8) {          // 2 independent gathers per lane
            GATHER_STEP(i + 0 + q)  GATHER_STEP(i + 4 + q)
        }
        for (; i < m; i += 4) {              // uniform tail, clamped source
            int idx = i + q;
            int safe = (idx < m) ? idx : i;
            int tt = __shfl(te, safe);
            float ww = __shfl(we, safe);
            ww = (idx < m) ? ww : 0.f;
            unsigned int u = *(const unsigned int*)(h16 + ((size_t)tt << 5) + (f2 << 1));
            num0 += ww * __uint_as_float(u << 16);
            num1 += ww * __uint_as_float(u & 0xFFFF0000u);
            den += ww;
        }
#undef GATHER_STEP
    }
    // reduce across the 4 quarters (lanes f2, f2+16, f2+32, f2+48)
    num0 += __shfl_xor(num0, 16); num0 += __shfl_xor(num0, 32);
    num1 += __shfl_xor(num1, 16); num1 += __shfl_xor(num1, 32);
    den  += __shfl_xor(den, 16);  den  += __shfl_xor(den, 32);
    float inv = 1.f / (den + 1e-10f);
    return make_float2(num0 * inv, num1 * inv);
}

// Final aggregate: one 64-lane wave per node; ELU fused; single float2 write.
__global__ void k_node_aggregate(const int* __restrict__ csr_tgt,
                                 const int* __restrict__ offsets, const int* __restrict__ counts,
                                 const float* __restrict__ s_src_irr, const float* __restrict__ s_tgt_irr,
                                 const float* __restrict__ s_src_sol, const float* __restrict__ s_tgt_sol,
                                 const unsigned short* __restrict__ h16_irr,
                                 const unsigned short* __restrict__ h16_sol,
                                 float* __restrict__ out) {
    int wave = threadIdx.x >> 6;
    int lane = threadIdx.x & 63;
    int n = blockIdx.x * 4 + wave;     // grid 25000 exact
    int f2 = lane & 15;
    int q = lane >> 4;

    float2 a = branch_acc(n, n, lane, f2, q, csr_tgt, offsets, counts,
                          s_src_irr, s_tgt_irr, h16_irr);
    float2 b = branch_acc(N_CELLS + n, n, lane, f2, q, csr_tgt, offsets, counts,
                          s_src_sol, s_tgt_sol, h16_sol);
    float r0 = a.x + b.x;
    float r1 = a.y + b.y;
    r0 = r0 > 0.f ? r0 : __expf(r0) - 1.f;   // ELU
    r1 = r1 > 0.f ? r1 : __expf(r1) - 1.f;
    if (q == 0) {
        float2* o2 = (float2*)(out + (size_t)n * FDIM);
        o2[f2] = make_float2(r0, r1);
    }
}

extern "C" void kernel_launch(void* const* d_in, const int* in_sizes, int n_in,
                              void* d_out, int out_size, void* d_ws, size_t ws_size,
                              hipStream_t stream) {
    const float* x = (const float*)d_in[0];
    const int* do_index = (const int*)d_in[1];
    const int* up_index = (const int*)d_in[2];
    const float* Wirr = (const float*)d_in[3];
    const float* Wsol = (const float*)d_in[4];
    const float* att_irr = (const float*)d_in[5];
    const float* att_sol = (const float*)d_in[6];
    float* out = (float*)d_out;

    // Workspace partition
    unsigned short* h16_irr = (unsigned short*)d_ws;               // N*F bf16
    unsigned short* h16_sol = h16_irr + (size_t)N_CELLS * FDIM;    // N*F bf16
    float* s_src_irr = (float*)(h16_sol + (size_t)N_CELLS * FDIM); // N
    float* s_tgt_irr = s_src_irr + N_CELLS;              // N
    float* s_src_sol = s_tgt_irr + N_CELLS;              // N
    float* s_tgt_sol = s_src_sol + N_CELLS;              // N
    int* counts = (int*)(s_tgt_sol + N_CELLS);           // NSEG
    int* offsets = counts + NSEG;                        // NSEG
    int* bin_cursor = offsets + NSEG;                    // NBIN*16 (64B-padded)
    int* csr_tgt = bin_cursor + NBIN * 16;               // 2*N_EDGES
    unsigned int* bin_buf = (unsigned int*)(csr_tgt + 2 * N_EDGES);  // NBIN*BIN_STRIDE

    hipMemsetAsync(bin_cursor, 0, NBIN * 16 * sizeof(int), stream);

    // K1: h (bf16) + scores (pure streaming)
    hipLaunchKernelGGL(k_fused, dim3(N_CELLS / 8), dim3(256), 0, stream,
                       x, Wirr, Wsol, att_irr, att_sol,
                       h16_irr, h16_sol, s_src_irr, s_tgt_irr, s_src_sol, s_tgt_sol);

    // K2: bin edges into fixed-stride append logs
    hipLaunchKernelGGL(k_bin, dim3(BIN_BLOCKS), dim3(256), 0, stream,
                       do_index, up_index, bin_cursor, bin_buf);

    // K3: per-bin prefix + LDS histogram + scan + permute -> counts/offsets/csr_tgt
    hipLaunchKernelGGL(k_scatter3, dim3(NBIN), dim3(256), 0, stream,
                       bin_buf, bin_cursor, offsets, counts, csr_tgt);

    // K4: per-node aggregate + ELU (1 wave/node, 4 waves/block -> exact grid)
    hipLaunchKernelGGL(k_node_aggregate, dim3(N_CELLS / 4), dim3(256), 0, stream,
                       csr_tgt, offsets, counts,
                       s_src_irr, s_tgt_irr, s_src_sol, s_tgt_sol,
                       h16_irr, h16_sol, out);
}

// Round 11
// 161.398 us; speedup vs baseline: 3.2821x; 1.1924x over previous
//
#include <hip/hip_runtime.h>
#include <math.h>

#define N_CELLS 100000
#define N_EDGES 1600000
#define FDIM 32
#define NEG_SLOPE 0.2f
#define NSEG (2 * N_CELLS)          // segments: both branches concatenated
#define NBIN 250
#define SEG_PER_BIN 800             // 250*800 = 200000 == NSEG exactly; local < 800 -> 10 bits
#define BIN_STRIDE 16000            // fixed slack region per bin (expected 12800, +25 sigma)
#define LDSCAP 14336                // LDS permute capacity (expected 12800, +12 sigma; fallback beyond)
#define EPT 16                      // edges per thread in k_bin
#define BIN_BLOCKS ((2 * N_EDGES + 256 * EPT - 1) / (256 * EPT))   // 782

__device__ __forceinline__ float leaky(float v) {
    return v > 0.f ? v : NEG_SLOPE * v;
}
// RNE f32 -> bf16 (values are normal floats; no NaN handling needed)
__device__ __forceinline__ unsigned short f32_to_bf16(float f) {
    unsigned int b = __float_as_uint(f);
    unsigned int r = b + 0x7FFFu + ((b >> 16) & 1u);
    return (unsigned short)(r >> 16);
}
__device__ __forceinline__ unsigned int float_to_ordered(float f) {
    unsigned int b = __float_as_uint(f);
    return (b & 0x80000000u) ? ~b : (b | 0x80000000u);
}
__device__ __forceinline__ float ordered_to_float(unsigned int u) {
    unsigned int b = (u & 0x80000000u) ? (u ^ 0x80000000u) : ~u;
    return __uint_as_float(b);
}

// Kernel 1: h = x@W (both branches, stored bf16) + per-node attention scores.
// Pure streaming: reads x once, writes h16/s coalesced. No atomics, no edges.
__global__ void k_fused(const float* __restrict__ x,
                        const float* __restrict__ Wirr, const float* __restrict__ Wsol,
                        const float* __restrict__ att_irr, const float* __restrict__ att_sol,
                        unsigned short* __restrict__ h16_irr, unsigned short* __restrict__ h16_sol,
                        float* __restrict__ s_src_irr, float* __restrict__ s_tgt_irr,
                        float* __restrict__ s_src_sol, float* __restrict__ s_tgt_sol) {
    __shared__ float sWirr[FDIM * FDIM], sWsol[FDIM * FDIM];
    __shared__ float sAi[2 * FDIM], sAs[2 * FDIM];
    int t = threadIdx.x;
    for (int i = t; i < FDIM * FDIM; i += 256) { sWirr[i] = Wirr[i]; sWsol[i] = Wsol[i]; }
    if (t < 2 * FDIM) { sAi[t] = att_irr[t]; sAs[t] = att_sol[t]; }
    __syncthreads();

    int wave = t >> 6, lane = t & 63, halfsel = lane >> 5, f = lane & 31;
    int row = blockIdx.x * 8 + wave * 2 + halfsel;    // grid 12500 x 8 rows exact
    const float* xr = x + (size_t)row * FDIM;
    float hi = 0.f, hs = 0.f;
#pragma unroll
    for (int k = 0; k < FDIM; ++k) {
        float xv = xr[k];
        hi += xv * sWirr[k * FDIM + f];
        hs += xv * sWsol[k * FDIM + f];
    }
    h16_irr[(size_t)row * FDIM + f] = f32_to_bf16(hi);
    h16_sol[(size_t)row * FDIM + f] = f32_to_bf16(hs);

    float pi0 = hi * sAi[f], pi1 = hi * sAi[FDIM + f];
    float ps0 = hs * sAs[f], ps1 = hs * sAs[FDIM + f];
#pragma unroll
    for (int m = 16; m >= 1; m >>= 1) {
        pi0 += __shfl_xor(pi0, m);
        pi1 += __shfl_xor(pi1, m);
        ps0 += __shfl_xor(ps0, m);
        ps1 += __shfl_xor(ps1, m);
    }
    if (f == 0) {
        s_src_irr[row] = pi0;
        s_tgt_irr[row] = pi1;
        s_src_sol[row] = ps0;
        s_tgt_sol[row] = ps1;
    }
}

// k_gmax: maxima of the 4 contiguous score arrays (s_src_irr, s_tgt_irr,
// s_src_sol, s_tgt_sol). 64 blocks per array; one line-padded ordered-uint
// atomicMax per block.
__global__ void k_gmax(const float* __restrict__ s_all, unsigned int* __restrict__ gmax_u) {
    int a = blockIdx.x & 3;
    const float* arr = s_all + (size_t)a * N_CELLS;
    float v = -INFINITY;
    for (int i = (blockIdx.x >> 2) * 256 + threadIdx.x; i < N_CELLS; i += 64 * 256)
        v = fmaxf(v, arr[i]);
#pragma unroll
    for (int m = 32; m >= 1; m >>= 1) v = fmaxf(v, __shfl_xor(v, m));
    __shared__ float sm[4];
    int lane = threadIdx.x & 63, w = threadIdx.x >> 6;
    if (lane == 0) sm[w] = v;
    __syncthreads();
    if (threadIdx.x == 0) {
        float b = fmaxf(fmaxf(sm[0], sm[1]), fmaxf(sm[2], sm[3]));
        atomicMax(&gmax_u[a * 16], float_to_ordered(b));
    }
}

// k_bin: append packed (local_seg,tgt) records to 250 fixed-stride bins.
// Block-aggregated appends (LDS slot assignment + one global atomic per
// block per bin on line-padded cursors): each bin is an append-only log,
// lines fill densely in time and write back once.
__global__ void k_bin(const int* __restrict__ do_idx, const int* __restrict__ up_idx,
                      int* __restrict__ bin_cursor, unsigned int* __restrict__ bin_buf) {
    __shared__ unsigned int lcount[NBIN];
    __shared__ unsigned int lbase[NBIN];
    int t = threadIdx.x;
    for (int i = t; i < NBIN; i += 256) lcount[i] = 0u;
    __syncthreads();

    unsigned int recs[EPT];
    short binsv[EPT];
    unsigned short slots[EPT];
    int base = blockIdx.x * (256 * EPT);
#pragma unroll
    for (int j = 0; j < EPT; ++j) {
        int tid = base + j * 256 + t;     // coalesced per j
        binsv[j] = -1;
        if (tid < 2 * N_EDGES) {
            int seg, tg;
            if (tid < N_EDGES) {
                seg = do_idx[tid];
                tg = do_idx[N_EDGES + tid];
            } else {
                int e = tid - N_EDGES;
                seg = N_CELLS + up_idx[e];
                tg = up_idx[N_EDGES + e];
            }
            int bin = seg / SEG_PER_BIN;
            int local = seg - bin * SEG_PER_BIN;          // < 800 -> 10 bits
            recs[j] = ((unsigned int)local << 17) | (unsigned int)tg;  // tgt < 2^17
            binsv[j] = (short)bin;
            slots[j] = (unsigned short)atomicAdd(&lcount[bin], 1u);
        }
    }
    __syncthreads();
    for (int i = t; i < NBIN; i += 256)
        lbase[i] = (unsigned int)(i * BIN_STRIDE) +
                   (unsigned int)atomicAdd(&bin_cursor[i * 16], (int)lcount[i]);
    __syncthreads();
#pragma unroll
    for (int j = 0; j < EPT; ++j)
        if (binsv[j] >= 0)
            bin_buf[lbase[binsv[j]] + slots[j]] = recs[j];
}

// k_scatter3: one workgroup per bin. Computes its own output prefix (scan of
// the 250 bin lengths in LDS), streams the bin's records, LDS-histograms the
// 800 local segments, LDS-scans for local offsets, writes counts/offsets
// coalesced, then permutes records into LDS and dumps -> csr_tgt
// sequentially: every global write coalesced, written exactly once.
__global__ void k_scatter3(const unsigned int* __restrict__ bin_buf,
                           const int* __restrict__ bin_cursor,
                           int* __restrict__ offsets, int* __restrict__ counts,
                           int* __restrict__ csr_tgt) {
    __shared__ int hist[SEG_PER_BIN];
    __shared__ int lofs[SEG_PER_BIN];
    __shared__ int ss[256];
    __shared__ int buf[LDSCAP];
    int bin = blockIdx.x;
    int t = threadIdx.x;
    int len = bin_cursor[bin * 16];
    int rbase = bin * BIN_STRIDE;
    int seg0 = bin * SEG_PER_BIN;

    // exclusive prefix of bin lengths -> outstart
    int partial = 0;
    for (int i = t; i < bin; i += 256) partial += bin_cursor[i * 16];
    ss[t] = partial;
    __syncthreads();
    for (int off = 128; off > 0; off >>= 1) {
        if (t < off) ss[t] += ss[t + off];
        __syncthreads();
    }
    int outstart = ss[0];
    __syncthreads();   // ss reused below

    for (int i = t; i < SEG_PER_BIN; i += 256) hist[i] = 0;
    __syncthreads();
    for (int idx = t; idx < len; idx += 256)
        atomicAdd(&hist[bin_buf[rbase + idx] >> 17], 1);
    __syncthreads();

    // exclusive scan of hist[0..800): 4 elems/thread + block scan of sums
    int b4 = t * 4;
    int v0 = 0, v1 = 0, v2 = 0, v3 = 0, sum = 0;
    if (b4 < SEG_PER_BIN) {
        v0 = hist[b4]; v1 = hist[b4 + 1]; v2 = hist[b4 + 2]; v3 = hist[b4 + 3];
        sum = v0 + v1 + v2 + v3;
    }
    ss[t] = sum;
    __syncthreads();
    for (int off = 1; off < 256; off <<= 1) {
        int xv = (t >= off) ? ss[t - off] : 0;
        __syncthreads();
        ss[t] += xv;
        __syncthreads();
    }
    int excl = (t == 0) ? 0 : ss[t - 1];
    if (b4 < SEG_PER_BIN) {
        lofs[b4] = excl;
        lofs[b4 + 1] = excl + v0;
        lofs[b4 + 2] = excl + v0 + v1;
        lofs[b4 + 3] = excl + v0 + v1 + v2;
    }
    __syncthreads();

    // counts / offsets (coalesced; 250*800 == NSEG exactly)
    for (int i = t; i < SEG_PER_BIN; i += 256) {
        offsets[seg0 + i] = outstart + lofs[i];
        counts[seg0 + i] = hist[i];
    }
    __syncthreads();

    if (len <= LDSCAP) {
        for (int idx = t; idx < len; idx += 256) {
            unsigned int rec = bin_buf[rbase + idx];
            int pos = atomicAdd(&lofs[rec >> 17], 1);
            buf[pos] = (int)(rec & 0x1FFFFu);
        }
        __syncthreads();
        for (int i = t; i < len; i += 256) csr_tgt[outstart + i] = buf[i];
    } else {
        for (int idx = t; idx < len; idx += 256) {
            unsigned int rec = bin_buf[rbase + idx];
            int pos = outstart + atomicAdd(&lofs[rec >> 17], 1);
            csr_tgt[pos] = (int)(rec & 0x1FFFFu);
        }
    }
}

// Per-branch accumulation, quarter-per-node. The 16 lanes of a quarter all
// process the SAME edge (broadcast csr/s_tgt loads, redundant weight
// computation -- VALU-parallel, zero cross-lane ops); each lane owns one
// packed bf16 feature pair of the h row. 4-edge unroll -> 16 independent
// 64B gathers in flight per wave. Global shift M (upper bound on every edge
// score) removes the online-max machinery; den >= exp(-(M - seg_max)), so
// the 1e-10 epsilon effect stays < ~2e-7 relative.
__device__ __forceinline__ void branch_acc(int seg, float ssrc, int f2,
                                           const int* __restrict__ csr_tgt,
                                           const int* __restrict__ offsets,
                                           const int* __restrict__ counts,
                                           const float* __restrict__ s_tgt,
                                           const unsigned short* __restrict__ h16,
                                           float M,
                                           float& num0, float& num1, float& den) {
    int beg = offsets[seg];
    int deg = counts[seg];
    num0 = 0.f; num1 = 0.f; den = 0.f;
    float b = ssrc - 0.f;   // keep ssrc in a register
    int i = 0;
#define EDGE_STEP(TT)                                                           \
        {                                                                       \
            float ev = leaky(b + s_tgt[(TT)]) - M;                              \
            float ww = __expf(ev);                                              \
            unsigned int u = *(const unsigned int*)(h16 + ((size_t)(TT) << 5) + (f2 << 1)); \
            num0 += ww * __uint_as_float(u << 16);                              \
            num1 += ww * __uint_as_float(u & 0xFFFF0000u);                      \
            den += ww;                                                          \
        }
    for (; i + 3 < deg; i += 4) {
        int t0 = csr_tgt[beg + i];
        int t1 = csr_tgt[beg + i + 1];
        int t2 = csr_tgt[beg + i + 2];
        int t3 = csr_tgt[beg + i + 3];
        EDGE_STEP(t0) EDGE_STEP(t1) EDGE_STEP(t2) EDGE_STEP(t3)
    }
    for (; i < deg; ++i) {
        int t0 = csr_tgt[beg + i];
        EDGE_STEP(t0)
    }
#undef EDGE_STEP
}

// Final aggregate: one 16-lane quarter per node (4 nodes/wave, 16/block);
// both branches sequential (independent load streams); ELU fused; one
// float2 write per lane -> 256B contiguous per wave.
__global__ void k_node_aggregate(const int* __restrict__ csr_tgt,
                                 const int* __restrict__ offsets, const int* __restrict__ counts,
                                 const float* __restrict__ s_src_irr, const float* __restrict__ s_tgt_irr,
                                 const float* __restrict__ s_src_sol, const float* __restrict__ s_tgt_sol,
                                 const unsigned short* __restrict__ h16_irr,
                                 const unsigned short* __restrict__ h16_sol,
                                 const unsigned int* __restrict__ gmax_u,
                                 float* __restrict__ out) {
    int t = threadIdx.x;
    int wave = t >> 6, lane = t & 63;
    int q = lane >> 4, f2 = lane & 15;
    int n = (blockIdx.x * 4 + wave) * 4 + q;     // grid 6250 exact
    float M0 = leaky(ordered_to_float(gmax_u[0]) + ordered_to_float(gmax_u[16]));
    float M1 = leaky(ordered_to_float(gmax_u[32]) + ordered_to_float(gmax_u[48]));

    float a0, a1, ad, b0, b1, bd;
    branch_acc(n, s_src_irr[n], f2, csr_tgt, offsets, counts,
               s_tgt_irr, h16_irr, M0, a0, a1, ad);
    branch_acc(N_CELLS + n, s_src_sol[n], f2, csr_tgt, offsets, counts,
               s_tgt_sol, h16_sol, M1, b0, b1, bd);
    float r0 = a0 / (ad + 1e-10f) + b0 / (bd + 1e-10f);
    float r1 = a1 / (ad + 1e-10f) + b1 / (bd + 1e-10f);
    r0 = r0 > 0.f ? r0 : __expf(r0) - 1.f;   // ELU
    r1 = r1 > 0.f ? r1 : __expf(r1) - 1.f;
    float2* o2 = (float2*)(out + (size_t)n * FDIM);
    o2[f2] = make_float2(r0, r1);
}

extern "C" void kernel_launch(void* const* d_in, const int* in_sizes, int n_in,
                              void* d_out, int out_size, void* d_ws, size_t ws_size,
                              hipStream_t stream) {
    const float* x = (const float*)d_in[0];
    const int* do_index = (const int*)d_in[1];
    const int* up_index = (const int*)d_in[2];
    const float* Wirr = (const float*)d_in[3];
    const float* Wsol = (const float*)d_in[4];
    const float* att_irr = (const float*)d_in[5];
    const float* att_sol = (const float*)d_in[6];
    float* out = (float*)d_out;

    // Workspace partition
    unsigned short* h16_irr = (unsigned short*)d_ws;               // N*F bf16
    unsigned short* h16_sol = h16_irr + (size_t)N_CELLS * FDIM;    // N*F bf16
    float* s_src_irr = (float*)(h16_sol + (size_t)N_CELLS * FDIM); // N
    float* s_tgt_irr = s_src_irr + N_CELLS;              // N
    float* s_src_sol = s_tgt_irr + N_CELLS;              // N
    float* s_tgt_sol = s_src_sol + N_CELLS;              // N
    int* counts = (int*)(s_tgt_sol + N_CELLS);           // NSEG
    int* offsets = counts + NSEG;                        // NSEG
    int* bin_cursor = offsets + NSEG;                    // NBIN*16 (64B-padded)
    unsigned int* gmax_u = (unsigned int*)(bin_cursor + NBIN * 16); // 4*16 padded
    int* csr_tgt = (int*)(gmax_u + 64);                  // 2*N_EDGES
    unsigned int* bin_buf = (unsigned int*)(csr_tgt + 2 * N_EDGES);  // NBIN*BIN_STRIDE

    // bin cursors + gmax (ordered-uint 0 == -inf) zeroed in one shot
    hipMemsetAsync(bin_cursor, 0, (NBIN * 16 + 64) * sizeof(int), stream);

    // K1: h (bf16) + scores (pure streaming)
    hipLaunchKernelGGL(k_fused, dim3(N_CELLS / 8), dim3(256), 0, stream,
                       x, Wirr, Wsol, att_irr, att_sol,
                       h16_irr, h16_sol, s_src_irr, s_tgt_irr, s_src_sol, s_tgt_sol);

    // K2: bin edges into fixed-stride append logs (independent of K1)
    hipLaunchKernelGGL(k_bin, dim3(BIN_BLOCKS), dim3(256), 0, stream,
                       do_index, up_index, bin_cursor, bin_buf);

    // K3: global maxima of the 4 score arrays
    hipLaunchKernelGGL(k_gmax, dim3(256), dim3(256), 0, stream, s_src_irr, gmax_u);

    // K4: per-bin prefix + LDS histogram + scan + permute -> counts/offsets/csr_tgt
    hipLaunchKernelGGL(k_scatter3, dim3(NBIN), dim3(256), 0, stream,
                       bin_buf, bin_cursor, offsets, counts, csr_tgt);

    // K5: per-node aggregate + ELU (quarter per node, grid 6250 exact)
    hipLaunchKernelGGL(k_node_aggregate, dim3(N_CELLS / 16), dim3(256), 0, stream,
                       csr_tgt, offsets, counts,
                       s_src_irr, s_tgt_irr, s_src_sol, s_tgt_sol,
                       h16_irr, h16_sol, gmax_u, out);
}